// Round 11
// baseline (482.607 us; speedup 1.0000x reference)
//
#include <hip/hip_runtime.h>
#include <cstdint>
#include <cstddef>

#define Nn 50000
#define Ne 800000
#define Ng 1024
#define NFd 32
#define Rr 4
#define Hd 64
#define Od 16
#define MAXD 10
#define NSEG (Nn * Rr)
#define SCAN_BLK ((NSEG + 255) / 256)
#define ORDER_SZ (Nn + 16 * (MAXD + 1))    // buckets padded to x16 (block-uniform d)
#define NB_MF (ORDER_SZ / 16)              // block = 4 waves x 4 slots, one bucket/block
#define NB_RG (Nn / 16)                    // block = 4 waves x 4 nodes
#define NB_GEMM ((Nn + 63) / 64)           // 782 blocks of 64 nodes
#define LDA 68                             // padded A leading dim (bank-conflict-free)

__device__ __forceinline__ float reluf(float v) { return v > 0.f ? v : 0.f; }
__device__ __forceinline__ int rfl(int v) { return __builtin_amdgcn_readfirstlane(v); }

// ---- per-edge relation argmax -> seg id + histogram + WITHIN-SEGMENT RANK ----
__global__ void k_rel_seg(const float4* __restrict__ ea, const int* __restrict__ eidx,
                          int* __restrict__ seg, int* __restrict__ rank,
                          int* __restrict__ cnt) {
    int e = blockIdx.x * 256 + threadIdx.x;
    if (e >= Ne) return;
    float4 a = ea[e];
    int bi = 0; float bv = a.x;
    if (a.y > bv) { bv = a.y; bi = 1; }
    if (a.z > bv) { bv = a.z; bi = 2; }
    if (a.w > bv) { bv = a.w; bi = 3; }
    int s = eidx[Ne + e] * Rr + bi;
    seg[e] = s;
    rank[e] = atomicAdd(&cnt[s], 1);
}

// ---- scan level 1 + fused degree histogram (deg(n) = sum of its 4 cnt entries) ----
__global__ void k_scan1(const int* __restrict__ cnt, int* __restrict__ off,
                        int* __restrict__ bsum, int* __restrict__ bcnt) {
    __shared__ int s[256];
    __shared__ int hist[16];
    int t = threadIdx.x;
    if (t < 16) hist[t] = 0;
    int idx = blockIdx.x * 256 + t;
    int v = (idx < NSEG) ? cnt[idx] : 0;
    s[t] = v;
    __syncthreads();
    if ((t & 3) == 0 && idx < NSEG) {
        int dsum = s[t] + s[t + 1] + s[t + 2] + s[t + 3];
        atomicAdd(&hist[min(dsum, MAXD)], 1);
    }
    #pragma unroll
    for (int o = 1; o < 256; o <<= 1) {
        int x = (t >= o) ? s[t - o] : 0;
        __syncthreads();
        s[t] += x;
        __syncthreads();
    }
    if (idx < NSEG) off[idx] = s[t] - v;            // exclusive
    if (t == 255) bsum[blockIdx.x] = s[255];
    if (t < 16) {
        int h = hist[t];
        if (h > 0) atomicAdd(&bcnt[t], h);
    }
}

// ---- scan level 2 + fused bucket prefix (16-aligned) + order pad-slot writes ----
__global__ void k_scan2(int* __restrict__ bsum, const int* __restrict__ bcnt,
                        int* __restrict__ bbase, int* __restrict__ order) {
    __shared__ int s[1024];
    int t = threadIdx.x;
    int v = (t < SCAN_BLK) ? bsum[t] : 0;
    s[t] = v;
    __syncthreads();
    #pragma unroll
    for (int o = 1; o < 1024; o <<= 1) {
        int x = (t >= o) ? s[t - o] : 0;
        __syncthreads();
        s[t] += x;
        __syncthreads();
    }
    if (t < SCAN_BLK) bsum[t] = s[t] - v;           // exclusive block bases
    if (t == 0) {
        int run = 0;
        for (int d = 0; d <= MAXD; d++) {
            int c = bcnt[d];
            bbase[d] = run;
            int pad = (c + 15) & ~15;
            for (int i = c; i < pad; i++) order[run + i] = -1;
            run += pad;
        }
        for (int i = run; i < ORDER_SZ; i++) order[i] = -1;
    }
}

__global__ void k_scan3(int* __restrict__ off, const int* __restrict__ bsum) {
    int idx = blockIdx.x * 256 + threadIdx.x;
    if (idx == 0) off[NSEG] = Ne;
    if (idx >= NSEG) return;
    off[idx] = off[idx] + bsum[blockIdx.x];
}

// ---- scatter edges into segment-sorted order: NO atomics (rank precomputed) ----
__global__ void k_scatter(const int* __restrict__ eidx, const int* __restrict__ seg,
                          const int* __restrict__ rank, const int* __restrict__ off,
                          int* __restrict__ sorted_src) {
    int e = blockIdx.x * 256 + threadIdx.x;
    if (e >= Ne) return;
    int pos = off[seg[e]] + rank[e];
    sorted_src[pos] = eidx[e];
}

// ---- embedding lookup: wave per node; writes relu'd row ----
__global__ void k_embed(const float* __restrict__ x, const float* __restrict__ emb,
                        float* __restrict__ h) {
    int wave = (blockIdx.x * 256 + threadIdx.x) >> 6;
    int lane = threadIdx.x & 63;
    if (wave >= Nn) return;
    float v = (lane < NFd) ? x[(size_t)wave * NFd + lane] : -1e30f;
    int idx = lane;
    #pragma unroll
    for (int off = 16; off >= 1; off >>= 1) {
        float ov = __shfl_down(v, off);
        int oi = __shfl_down(idx, off);
        if (ov > v || (ov == v && oi < idx)) { v = ov; idx = oi; }
    }
    idx = __shfl(idx, 0);
    h[(size_t)wave * Hd + lane] = reluf(emb[(size_t)idx * Hd + lane]);
}

// ---- bucket scatter: degree from one int4 of cnt; buckets 16-aligned ----
__global__ void k_bucket_scatter(const int4* __restrict__ cnt4, const int* __restrict__ bbase,
                                 int* __restrict__ bfill, int* __restrict__ order) {
    __shared__ int hist[16];
    __shared__ int base[16];
    if (threadIdx.x < 16) hist[threadIdx.x] = 0;
    __syncthreads();
    int n = blockIdx.x * 256 + threadIdx.x;
    int d = 0, rank = 0;
    bool valid = (n < Nn);
    if (valid) {
        int4 c = cnt4[n];
        d = min(c.x + c.y + c.z + c.w, MAXD);
        rank = atomicAdd(&hist[d], 1);
    }
    __syncthreads();
    if (threadIdx.x < 16) {
        int h = hist[threadIdx.x];
        base[threadIdx.x] = (h > 0) ? atomicAdd(&bfill[threadIdx.x], h) : 0;
    }
    __syncthreads();
    if (valid) order[bbase[d] + base[d] + rank] = n | (d << 20);
}

// classify edge ee via wave-uniform boundaries -> 4 uniform scalar scales
#define ACCS(v, ee)  {                                      \
    int rr = ((ee) >= e1) + ((ee) >= e2) + ((ee) >= e3);    \
    float s0 = (rr == 0) ? i0 : 0.f;                        \
    float s1 = (rr == 1) ? i1 : 0.f;                        \
    float s2 = (rr == 2) ? i2 : 0.f;                        \
    float s3 = (rr == 3) ? i3 : 0.f;                        \
    a0 = fmaf(s0, (v), a0);                                 \
    a1 = fmaf(s1, (v), a1);                                 \
    a2 = fmaf(s2, (v), a2);                                 \
    a3 = fmaf(s3, (v), a3); }

// ---- RGCN gather: 16-deep unrolled gather -> rel-major means aggR[r][n][64] ----
__global__ __launch_bounds__(256) void k_rgcn_gather(
        const float* __restrict__ hin, const int* __restrict__ off,
        const int* __restrict__ ssrc, float* __restrict__ aggR) {
    int tid = threadIdx.x;
    int wv = tid >> 6, lane = tid & 63;
    int wave = rfl(blockIdx.x * 4 + wv);
    int n0 = wave * 4;
    for (int i = 0; i < 4; i++) {
        int n = n0 + i;
        int nb = n * Rr;
        int e0 = rfl(off[nb]);
        int e1 = rfl(off[nb + 1]);
        int e2 = rfl(off[nb + 2]);
        int e3 = rfl(off[nb + 3]);
        int e4 = rfl(off[nb + 4]);
        float i0 = (e1 > e0) ? 1.f / (float)(e1 - e0) : 0.f;
        float i1 = (e2 > e1) ? 1.f / (float)(e2 - e1) : 0.f;
        float i2 = (e3 > e2) ? 1.f / (float)(e3 - e2) : 0.f;
        float i3 = (e4 > e3) ? 1.f / (float)(e4 - e3) : 0.f;
        float a0 = 0.f, a1 = 0.f, a2 = 0.f, a3 = 0.f;
        int e = e0;
        for (; e + 16 <= e4; e += 16) {             // 16 loads in flight
            const int4 sA = *(const int4*)(ssrc + e);
            const int4 sB = *(const int4*)(ssrc + e + 4);
            const int4 sC = *(const int4*)(ssrc + e + 8);
            const int4 sD = *(const int4*)(ssrc + e + 12);
            float v0 = hin[(size_t)sA.x * Hd + lane];
            float v1 = hin[(size_t)sA.y * Hd + lane];
            float v2 = hin[(size_t)sA.z * Hd + lane];
            float v3 = hin[(size_t)sA.w * Hd + lane];
            float v4 = hin[(size_t)sB.x * Hd + lane];
            float v5 = hin[(size_t)sB.y * Hd + lane];
            float v6 = hin[(size_t)sB.z * Hd + lane];
            float v7 = hin[(size_t)sB.w * Hd + lane];
            float v8 = hin[(size_t)sC.x * Hd + lane];
            float v9 = hin[(size_t)sC.y * Hd + lane];
            float vA = hin[(size_t)sC.z * Hd + lane];
            float vB = hin[(size_t)sC.w * Hd + lane];
            float vC = hin[(size_t)sD.x * Hd + lane];
            float vD = hin[(size_t)sD.y * Hd + lane];
            float vE = hin[(size_t)sD.z * Hd + lane];
            float vF = hin[(size_t)sD.w * Hd + lane];
            ACCS(v0, e + 0);  ACCS(v1, e + 1);  ACCS(v2, e + 2);  ACCS(v3, e + 3);
            ACCS(v4, e + 4);  ACCS(v5, e + 5);  ACCS(v6, e + 6);  ACCS(v7, e + 7);
            ACCS(v8, e + 8);  ACCS(v9, e + 9);  ACCS(vA, e + 10); ACCS(vB, e + 11);
            ACCS(vC, e + 12); ACCS(vD, e + 13); ACCS(vE, e + 14); ACCS(vF, e + 15);
        }
        for (; e + 4 <= e4; e += 4) {
            const int4 sA = *(const int4*)(ssrc + e);
            float v0 = hin[(size_t)sA.x * Hd + lane];
            float v1 = hin[(size_t)sA.y * Hd + lane];
            float v2 = hin[(size_t)sA.z * Hd + lane];
            float v3 = hin[(size_t)sA.w * Hd + lane];
            ACCS(v0, e + 0); ACCS(v1, e + 1); ACCS(v2, e + 2); ACCS(v3, e + 3);
        }
        for (; e < e4; e++) {
            int s = rfl(ssrc[e]);
            float v = hin[(size_t)s * Hd + lane];
            ACCS(v, e);
        }
        aggR[((size_t)0 * Nn + n) * Hd + lane] = a0;   // means (inv folded)
        aggR[((size_t)1 * Nn + n) * Hd + lane] = a1;
        aggR[((size_t)2 * Nn + n) * Hd + lane] = a2;
        aggR[((size_t)3 * Nn + n) * Hd + lane] = a3;
    }
}

// ---- RGCN transform as tiled GEMM: out = relu(b + [hin|mean0..3] @ [Wroot;W]) ----
__global__ __launch_bounds__(256) void k_rgcn_gemm(
        const float* __restrict__ hin, const float* __restrict__ aggR,
        const float* __restrict__ W, const float* __restrict__ Wroot,
        const float* __restrict__ bias, float* __restrict__ hout) {
    __shared__ float As[64 * LDA];                  // 17 KB, padded rows
    __shared__ float Bs[64 * 64];                   // 16 KB
    int tid = threadIdx.x;
    int n0 = blockIdx.x * 64;
    int wv = tid >> 6, lane = tid & 63;
    int r = lane >> 4, c = lane & 15;
    int row_base = wv * 16 + 4 * r;                 // 4 consecutive A rows per lane
    float acc[4][4];
    #pragma unroll
    for (int i = 0; i < 4; i++)
        #pragma unroll
        for (int j = 0; j < 4; j++) acc[i][j] = 0.f;
    for (int p = 0; p < 5; p++) {
        const float* Bsrc = (p == 0) ? Wroot : (W + (size_t)(p - 1) * Hd * Hd);
        #pragma unroll
        for (int q = 0; q < 4; q++) {
            int idx = q * 256 + tid;                // 0..1023 float4 slots
            int arow = idx >> 4;
            int ac4 = idx & 15;
            int n = n0 + arow; if (n >= Nn) n = Nn - 1;
            const float* asrc = (p == 0) ? (hin + (size_t)n * Hd)
                                         : (aggR + ((size_t)(p - 1) * Nn + n) * Hd);
            *(float4*)&As[arow * LDA + ac4 * 4] = *(const float4*)(asrc + ac4 * 4);
            *(float4*)&Bs[idx * 4] = *(const float4*)(Bsrc + idx * 4);
        }
        __syncthreads();
        for (int k4 = 0; k4 < 64; k4 += 4) {
            float4 aa[4], bb[4];
            #pragma unroll
            for (int i = 0; i < 4; i++)
                aa[i] = *(float4*)&As[(row_base + i) * LDA + k4];
            #pragma unroll
            for (int kk = 0; kk < 4; kk++)
                bb[kk] = *(float4*)&Bs[(k4 + kk) * 64 + c * 4];
            #pragma unroll
            for (int i = 0; i < 4; i++) {
                acc[i][0] += aa[i].x * bb[0].x + aa[i].y * bb[1].x
                           + aa[i].z * bb[2].x + aa[i].w * bb[3].x;
                acc[i][1] += aa[i].x * bb[0].y + aa[i].y * bb[1].y
                           + aa[i].z * bb[2].y + aa[i].w * bb[3].y;
                acc[i][2] += aa[i].x * bb[0].z + aa[i].y * bb[1].z
                           + aa[i].z * bb[2].z + aa[i].w * bb[3].z;
                acc[i][3] += aa[i].x * bb[0].w + aa[i].y * bb[1].w
                           + aa[i].z * bb[2].w + aa[i].w * bb[3].w;
            }
        }
        __syncthreads();
    }
    float4 bj = *(const float4*)(bias + c * 4);
    #pragma unroll
    for (int i = 0; i < 4; i++) {
        int n = n0 + row_base + i;
        if (n < Nn) {
            float4 o;
            o.x = reluf(acc[i][0] + bj.x);
            o.y = reluf(acc[i][1] + bj.y);
            o.z = reluf(acc[i][2] + bj.z);
            o.w = reluf(acc[i][3] + bj.w);
            *(float4*)&hout[(size_t)n * Hd + c * 4] = o;
        }
    }
}

// ---- FUSED MFConv: gather + bucketed transform; block-uniform degree so
// Wl[d],Wr[d] are staged once per block into LDS (buckets 16-aligned) ----
__global__ __launch_bounds__(256) void k_mf_fused(
        const float* __restrict__ hin, const int* __restrict__ off,
        const int* __restrict__ ssrc, const int* __restrict__ order,
        const float* __restrict__ Wl, const float* __restrict__ bl,
        const float* __restrict__ Wr, float* __restrict__ hout, int relu_out) {
    __shared__ float wlds[2 * Hd * Hd];             // 32 KB staged weights
    __shared__ float sums[4][4][Hd];                // 4 KB gathered neighbor sums
    int tid = threadIdx.x;
    int ef = order[blockIdx.x * 16];                // first slot: block-uniform bucket
    if (ef < 0) return;                             // all-pad block (uniform return)
    int d = ef >> 20;
    {   // stage weights; loads issue early and overlap the gather below
        const float4* wl4 = (const float4*)(Wl + (size_t)d * Hd * Hd);
        const float4* wr4 = (const float4*)(Wr + (size_t)d * Hd * Hd);
        float4* dl = (float4*)wlds;
        float4* dr = (float4*)(wlds + Hd * Hd);
        #pragma unroll
        for (int q = 0; q < 4; q++) dl[q * 256 + tid] = wl4[q * 256 + tid];
        #pragma unroll
        for (int q = 0; q < 4; q++) dr[q * 256 + tid] = wr4[q * 256 + tid];
    }
    int wv = tid >> 6, lane = tid & 63;
    int slot0 = rfl(blockIdx.x * 16 + wv * 4);
    int ent[4];
    #pragma unroll
    for (int i = 0; i < 4; i++) ent[i] = rfl(order[slot0 + i]);
    int n[4];
    #pragma unroll
    for (int i = 0; i < 4; i++) n[i] = (ent[i] >= 0) ? (ent[i] & 0xFFFFF) : 0;
    for (int i = 0; i < 4; i++) {
        int e0 = rfl(off[n[i] * Rr]);
        int e4 = rfl(off[n[i] * Rr + Rr]);
        float p0 = 0.f, p1 = 0.f, p2 = 0.f, p3 = 0.f;
        int e = e0;
        for (; e + 16 <= e4; e += 16) {
            const int4 sA = *(const int4*)(ssrc + e);
            const int4 sB = *(const int4*)(ssrc + e + 4);
            const int4 sC = *(const int4*)(ssrc + e + 8);
            const int4 sD = *(const int4*)(ssrc + e + 12);
            p0 += hin[(size_t)sA.x * Hd + lane] + hin[(size_t)sA.y * Hd + lane]
                + hin[(size_t)sA.z * Hd + lane] + hin[(size_t)sA.w * Hd + lane];
            p1 += hin[(size_t)sB.x * Hd + lane] + hin[(size_t)sB.y * Hd + lane]
                + hin[(size_t)sB.z * Hd + lane] + hin[(size_t)sB.w * Hd + lane];
            p2 += hin[(size_t)sC.x * Hd + lane] + hin[(size_t)sC.y * Hd + lane]
                + hin[(size_t)sC.z * Hd + lane] + hin[(size_t)sC.w * Hd + lane];
            p3 += hin[(size_t)sD.x * Hd + lane] + hin[(size_t)sD.y * Hd + lane]
                + hin[(size_t)sD.z * Hd + lane] + hin[(size_t)sD.w * Hd + lane];
        }
        for (; e + 4 <= e4; e += 4) {
            const int4 sA = *(const int4*)(ssrc + e);
            p0 += hin[(size_t)sA.x * Hd + lane] + hin[(size_t)sA.y * Hd + lane]
                + hin[(size_t)sA.z * Hd + lane] + hin[(size_t)sA.w * Hd + lane];
        }
        for (; e < e4; e++) {
            int s = rfl(ssrc[e]);
            p0 += hin[(size_t)s * Hd + lane];
        }
        sums[wv][i][lane] = (p0 + p1) + (p2 + p3);
    }
    __syncthreads();                                // weights staged + sums written
    float acc[4] = {0.f, 0.f, 0.f, 0.f};
    for (int kc = 0; kc < Hd; kc += 4) {
        float a0 = wlds[(kc + 0) * Hd + lane];
        float a1 = wlds[(kc + 1) * Hd + lane];
        float a2 = wlds[(kc + 2) * Hd + lane];
        float a3 = wlds[(kc + 3) * Hd + lane];
        float b0 = wlds[Hd * Hd + (kc + 0) * Hd + lane];
        float b1 = wlds[Hd * Hd + (kc + 1) * Hd + lane];
        float b2 = wlds[Hd * Hd + (kc + 2) * Hd + lane];
        float b3 = wlds[Hd * Hd + (kc + 3) * Hd + lane];
        #pragma unroll
        for (int i = 0; i < 4; i++) {
            const float4 av = *(const float4*)(&sums[wv][i][kc]);
            const float4 hv = *(const float4*)(hin + (size_t)n[i] * Hd + kc);
            acc[i] += av.x * a0 + av.y * a1 + av.z * a2 + av.w * a3
                    + hv.x * b0 + hv.y * b1 + hv.z * b2 + hv.w * b3;
        }
    }
    float bb = bl[d * Hd + lane];
    #pragma unroll
    for (int i = 0; i < 4; i++)
        if (ent[i] >= 0) {
            float v = acc[i] + bb;
            hout[(size_t)n[i] * Hd + lane] = relu_out ? reluf(v) : v;
        }
}

// ---- global add pool (batch_idx is sorted -> mostly single fused atomic) ----
__global__ void k_pool(const float* __restrict__ h, const int* __restrict__ batch,
                       float* __restrict__ g) {
    int wave = rfl((blockIdx.x * 256 + threadIdx.x) >> 6);
    int lane = threadIdx.x & 63;
    int n0 = wave * 4;
    if (n0 >= Nn) return;
    int b0 = batch[n0], b1 = batch[n0 + 1], b2 = batch[n0 + 2], b3 = batch[n0 + 3];
    float v0 = h[(size_t)n0 * Hd + lane];
    float v1 = h[(size_t)(n0 + 1) * Hd + lane];
    float v2 = h[(size_t)(n0 + 2) * Hd + lane];
    float v3 = h[(size_t)(n0 + 3) * Hd + lane];
    if (b0 == b1 && b0 == b2 && b0 == b3) {
        unsafeAtomicAdd(&g[(size_t)b0 * Hd + lane], v0 + v1 + v2 + v3);
    } else {
        unsafeAtomicAdd(&g[(size_t)b0 * Hd + lane], v0);
        unsafeAtomicAdd(&g[(size_t)b1 * Hd + lane], v1);
        unsafeAtomicAdd(&g[(size_t)b2 * Hd + lane], v2);
        unsafeAtomicAdd(&g[(size_t)b3 * Hd + lane], v3);
    }
}

// ---- head: relu(g@lin1+b1)@lin2+b2, one wave per graph ----
__global__ void k_head(const float* __restrict__ g, const float* __restrict__ w1,
                       const float* __restrict__ b1, const float* __restrict__ w2,
                       const float* __restrict__ b2, float* __restrict__ out) {
    __shared__ float t[4][Hd];
    int wv = threadIdx.x >> 6;
    int lane = threadIdx.x & 63;
    int gi = blockIdx.x * 4 + wv;
    float acc = b1[lane];
    for (int k = 0; k < Hd; k++) acc += g[(size_t)gi * Hd + k] * w1[k * Hd + lane];
    t[wv][lane] = reluf(acc);
    __syncthreads();
    if (lane < Od) {
        float o = b2[lane];
        for (int k = 0; k < Hd; k++) o += t[wv][k] * w2[k * Od + lane];
        out[(size_t)gi * Od + lane] = o;
    }
}

extern "C" void kernel_launch(void* const* d_in, const int* in_sizes, int n_in,
                              void* d_out, int out_size, void* d_ws, size_t ws_size,
                              hipStream_t stream) {
    const float* x      = (const float*)d_in[0];
    const float* ea     = (const float*)d_in[1];
    const int*   eidx   = (const int*)d_in[2];
    const int*   batch  = (const int*)d_in[3];
    const float* emb    = (const float*)d_in[4];
    const float* lin1_w = (const float*)d_in[5];
    const float* lin1_b = (const float*)d_in[6];
    const float* lin2_w = (const float*)d_in[7];
    const float* lin2_b = (const float*)d_in[8];
    const float* rgcn_w[2]    = {(const float*)d_in[9],  (const float*)d_in[15]};
    const float* rgcn_root[2] = {(const float*)d_in[10], (const float*)d_in[16]};
    const float* rgcn_b[2]    = {(const float*)d_in[11], (const float*)d_in[17]};
    const float* mf_wl[2]     = {(const float*)d_in[12], (const float*)d_in[18]};
    const float* mf_bl[2]     = {(const float*)d_in[13], (const float*)d_in[19]};
    const float* mf_wr[2]     = {(const float*)d_in[14], (const float*)d_in[20]};

    char* p = (char*)d_ws;
    float* h0   = (float*)p; p += sizeof(float) * (size_t)Nn * Hd;
    float* h1   = (float*)p; p += sizeof(float) * (size_t)Nn * Hd;
    float* aggR = (float*)p; p += sizeof(float) * (size_t)Rr * Nn * Hd;
    float* gbuf = (float*)p; p += sizeof(float) * (size_t)Ng * Hd;
    int* seg    = (int*)p;   p += sizeof(int) * (size_t)Ne;
    int* rank   = (int*)p;   p += sizeof(int) * (size_t)Ne;
    int* ssrc   = (int*)p;   p += sizeof(int) * (size_t)Ne;
    int* cnt    = (int*)p;   p += sizeof(int) * (size_t)NSEG;   // contiguous with bcnt/bfill
    int* bcnt   = (int*)p;   p += sizeof(int) * 16;
    int* bfill  = (int*)p;   p += sizeof(int) * 16;
    int* off    = (int*)p;   p += sizeof(int) * (size_t)(NSEG + 1);
    int* bsum   = (int*)p;   p += sizeof(int) * 1024;
    int* bbase  = (int*)p;   p += sizeof(int) * 16;
    int* order  = (int*)p;   p += sizeof(int) * (size_t)ORDER_SZ;

    hipMemsetAsync(cnt, 0, sizeof(int) * ((size_t)NSEG + 32), stream);
    hipMemsetAsync(gbuf, 0, sizeof(float) * (size_t)Ng * Hd, stream);

    k_rel_seg<<<Ne / 256, 256, 0, stream>>>((const float4*)ea, eidx, seg, rank, cnt);
    k_scan1<<<SCAN_BLK, 256, 0, stream>>>(cnt, off, bsum, bcnt);
    k_scan2<<<1, 1024, 0, stream>>>(bsum, bcnt, bbase, order);
    k_scan3<<<SCAN_BLK, 256, 0, stream>>>(off, bsum);
    k_scatter<<<Ne / 256, 256, 0, stream>>>(eidx, seg, rank, off, ssrc);
    k_embed<<<Nn / 4, 256, 0, stream>>>(x, emb, h0);
    k_bucket_scatter<<<(Nn + 255) / 256, 256, 0, stream>>>((const int4*)cnt, bbase, bfill, order);

    float* hin = h0;
    float* hout = h1;
    for (int b = 0; b < 2; b++) {
        k_rgcn_gather<<<NB_RG, 256, 0, stream>>>(hin, off, ssrc, aggR);
        k_rgcn_gemm<<<NB_GEMM, 256, 0, stream>>>(hin, aggR, rgcn_w[b], rgcn_root[b],
                                                 rgcn_b[b], hout);
        k_mf_fused<<<NB_MF, 256, 0, stream>>>(hout, off, ssrc, order, mf_wl[b],
                                              mf_bl[b], mf_wr[b], hin, b == 0 ? 1 : 0);
        // block output is back in hin for the next block (relu'd for b=0, raw for b=1)
    }
    k_pool<<<Nn / 16, 256, 0, stream>>>(hin, batch, gbuf);
    k_head<<<Ng / 4, 256, 0, stream>>>(gbuf, lin1_w, lin1_b, lin2_w, lin2_b, (float*)d_out);
}

// Round 12
// 453.398 us; speedup vs baseline: 1.0644x; 1.0644x over previous
//
#include <hip/hip_runtime.h>
#include <cstdint>
#include <cstddef>

#define Nn 50000
#define Ne 800000
#define Ng 1024
#define NFd 32
#define Rr 4
#define Hd 64
#define Od 16
#define MAXD 10
#define NSEG (Nn * Rr)
#define SCAN_BLK ((NSEG + 255) / 256)
#define ORDER_SZ (Nn + 48)                 // buckets padded to x4: max 11*3 pad
#define NB_MF ((ORDER_SZ + 15) / 16)       // block = 4 waves x 4 slots
#define NB_RG (Nn / 16)                    // block = 4 waves x 4 nodes
#define NB_GEMM ((Nn + 63) / 64)           // 782 blocks of 64 nodes
#define LDA 68                             // padded A leading dim (bank-conflict-free)

__device__ __forceinline__ float reluf(float v) { return v > 0.f ? v : 0.f; }
__device__ __forceinline__ int rfl(int v) { return __builtin_amdgcn_readfirstlane(v); }

// ---- per-edge relation argmax -> seg id + histogram + WITHIN-SEGMENT RANK ----
__global__ void k_rel_seg(const float4* __restrict__ ea, const int* __restrict__ eidx,
                          int* __restrict__ seg, int* __restrict__ rank,
                          int* __restrict__ cnt) {
    int e = blockIdx.x * 256 + threadIdx.x;
    if (e >= Ne) return;
    float4 a = ea[e];
    int bi = 0; float bv = a.x;
    if (a.y > bv) { bv = a.y; bi = 1; }
    if (a.z > bv) { bv = a.z; bi = 2; }
    if (a.w > bv) { bv = a.w; bi = 3; }
    int s = eidx[Ne + e] * Rr + bi;
    seg[e] = s;
    rank[e] = atomicAdd(&cnt[s], 1);
}

// ---- scan level 1 + fused degree histogram (deg(n) = sum of its 4 cnt entries) ----
__global__ void k_scan1(const int* __restrict__ cnt, int* __restrict__ off,
                        int* __restrict__ bsum, int* __restrict__ bcnt) {
    __shared__ int s[256];
    __shared__ int hist[16];
    int t = threadIdx.x;
    if (t < 16) hist[t] = 0;
    int idx = blockIdx.x * 256 + t;
    int v = (idx < NSEG) ? cnt[idx] : 0;
    s[t] = v;
    __syncthreads();
    if ((t & 3) == 0 && idx < NSEG) {
        int dsum = s[t] + s[t + 1] + s[t + 2] + s[t + 3];
        atomicAdd(&hist[min(dsum, MAXD)], 1);
    }
    #pragma unroll
    for (int o = 1; o < 256; o <<= 1) {
        int x = (t >= o) ? s[t - o] : 0;
        __syncthreads();
        s[t] += x;
        __syncthreads();
    }
    if (idx < NSEG) off[idx] = s[t] - v;            // exclusive
    if (t == 255) bsum[blockIdx.x] = s[255];
    if (t < 16) {
        int h = hist[t];
        if (h > 0) atomicAdd(&bcnt[t], h);
    }
}

// ---- scan level 2 + fused bucket prefix (4-aligned) + order pad-slot writes ----
__global__ void k_scan2(int* __restrict__ bsum, const int* __restrict__ bcnt,
                        int* __restrict__ bbase, int* __restrict__ order) {
    __shared__ int s[1024];
    int t = threadIdx.x;
    int v = (t < SCAN_BLK) ? bsum[t] : 0;
    s[t] = v;
    __syncthreads();
    #pragma unroll
    for (int o = 1; o < 1024; o <<= 1) {
        int x = (t >= o) ? s[t - o] : 0;
        __syncthreads();
        s[t] += x;
        __syncthreads();
    }
    if (t < SCAN_BLK) bsum[t] = s[t] - v;           // exclusive block bases
    if (t == 0) {
        int run = 0;
        for (int d = 0; d <= MAXD; d++) {
            int c = bcnt[d];
            bbase[d] = run;
            int pad = (c + 3) & ~3;
            for (int i = c; i < pad; i++) order[run + i] = -1;
            run += pad;
        }
        for (int i = run; i < ORDER_SZ; i++) order[i] = -1;
    }
}

__global__ void k_scan3(int* __restrict__ off, const int* __restrict__ bsum) {
    int idx = blockIdx.x * 256 + threadIdx.x;
    if (idx == 0) off[NSEG] = Ne;
    if (idx >= NSEG) return;
    off[idx] = off[idx] + bsum[blockIdx.x];
}

// ---- scatter edges into segment-sorted order: NO atomics (rank precomputed) ----
__global__ void k_scatter(const int* __restrict__ eidx, const int* __restrict__ seg,
                          const int* __restrict__ rank, const int* __restrict__ off,
                          int* __restrict__ sorted_src) {
    int e = blockIdx.x * 256 + threadIdx.x;
    if (e >= Ne) return;
    int pos = off[seg[e]] + rank[e];
    sorted_src[pos] = eidx[e];
}

// ---- embedding lookup: wave per node; writes relu'd row ----
__global__ void k_embed(const float* __restrict__ x, const float* __restrict__ emb,
                        float* __restrict__ h) {
    int wave = (blockIdx.x * 256 + threadIdx.x) >> 6;
    int lane = threadIdx.x & 63;
    if (wave >= Nn) return;
    float v = (lane < NFd) ? x[(size_t)wave * NFd + lane] : -1e30f;
    int idx = lane;
    #pragma unroll
    for (int off = 16; off >= 1; off >>= 1) {
        float ov = __shfl_down(v, off);
        int oi = __shfl_down(idx, off);
        if (ov > v || (ov == v && oi < idx)) { v = ov; idx = oi; }
    }
    idx = __shfl(idx, 0);
    h[(size_t)wave * Hd + lane] = reluf(emb[(size_t)idx * Hd + lane]);
}

// ---- bucket scatter: degree from one int4 of cnt; buckets 4-aligned ----
__global__ void k_bucket_scatter(const int4* __restrict__ cnt4, const int* __restrict__ bbase,
                                 int* __restrict__ bfill, int* __restrict__ order) {
    __shared__ int hist[16];
    __shared__ int base[16];
    if (threadIdx.x < 16) hist[threadIdx.x] = 0;
    __syncthreads();
    int n = blockIdx.x * 256 + threadIdx.x;
    int d = 0, rank = 0;
    bool valid = (n < Nn);
    if (valid) {
        int4 c = cnt4[n];
        d = min(c.x + c.y + c.z + c.w, MAXD);
        rank = atomicAdd(&hist[d], 1);
    }
    __syncthreads();
    if (threadIdx.x < 16) {
        int h = hist[threadIdx.x];
        base[threadIdx.x] = (h > 0) ? atomicAdd(&bfill[threadIdx.x], h) : 0;
    }
    __syncthreads();
    if (valid) order[bbase[d] + base[d] + rank] = n | (d << 20);
}

// classify edge ee via wave-uniform boundaries -> 4 uniform scalar scales
#define ACCS(v, ee)  {                                      \
    int rr = ((ee) >= e1) + ((ee) >= e2) + ((ee) >= e3);    \
    float s0 = (rr == 0) ? i0 : 0.f;                        \
    float s1 = (rr == 1) ? i1 : 0.f;                        \
    float s2 = (rr == 2) ? i2 : 0.f;                        \
    float s3 = (rr == 3) ? i3 : 0.f;                        \
    a0 = fmaf(s0, (v), a0);                                 \
    a1 = fmaf(s1, (v), a1);                                 \
    a2 = fmaf(s2, (v), a2);                                 \
    a3 = fmaf(s3, (v), a3); }

// ---- RGCN gather: 16-deep unrolled gather -> rel-major means aggR[r][n][64] ----
__global__ __launch_bounds__(256) void k_rgcn_gather(
        const float* __restrict__ hin, const int* __restrict__ off,
        const int* __restrict__ ssrc, float* __restrict__ aggR) {
    int tid = threadIdx.x;
    int wv = tid >> 6, lane = tid & 63;
    int wave = rfl(blockIdx.x * 4 + wv);
    int n0 = wave * 4;
    for (int i = 0; i < 4; i++) {
        int n = n0 + i;
        int nb = n * Rr;
        int e0 = rfl(off[nb]);
        int e1 = rfl(off[nb + 1]);
        int e2 = rfl(off[nb + 2]);
        int e3 = rfl(off[nb + 3]);
        int e4 = rfl(off[nb + 4]);
        float i0 = (e1 > e0) ? 1.f / (float)(e1 - e0) : 0.f;
        float i1 = (e2 > e1) ? 1.f / (float)(e2 - e1) : 0.f;
        float i2 = (e3 > e2) ? 1.f / (float)(e3 - e2) : 0.f;
        float i3 = (e4 > e3) ? 1.f / (float)(e4 - e3) : 0.f;
        float a0 = 0.f, a1 = 0.f, a2 = 0.f, a3 = 0.f;
        int e = e0;
        for (; e + 16 <= e4; e += 16) {             // 16 loads in flight
            const int4 sA = *(const int4*)(ssrc + e);
            const int4 sB = *(const int4*)(ssrc + e + 4);
            const int4 sC = *(const int4*)(ssrc + e + 8);
            const int4 sD = *(const int4*)(ssrc + e + 12);
            float v0 = hin[(size_t)sA.x * Hd + lane];
            float v1 = hin[(size_t)sA.y * Hd + lane];
            float v2 = hin[(size_t)sA.z * Hd + lane];
            float v3 = hin[(size_t)sA.w * Hd + lane];
            float v4 = hin[(size_t)sB.x * Hd + lane];
            float v5 = hin[(size_t)sB.y * Hd + lane];
            float v6 = hin[(size_t)sB.z * Hd + lane];
            float v7 = hin[(size_t)sB.w * Hd + lane];
            float v8 = hin[(size_t)sC.x * Hd + lane];
            float v9 = hin[(size_t)sC.y * Hd + lane];
            float vA = hin[(size_t)sC.z * Hd + lane];
            float vB = hin[(size_t)sC.w * Hd + lane];
            float vC = hin[(size_t)sD.x * Hd + lane];
            float vD = hin[(size_t)sD.y * Hd + lane];
            float vE = hin[(size_t)sD.z * Hd + lane];
            float vF = hin[(size_t)sD.w * Hd + lane];
            ACCS(v0, e + 0);  ACCS(v1, e + 1);  ACCS(v2, e + 2);  ACCS(v3, e + 3);
            ACCS(v4, e + 4);  ACCS(v5, e + 5);  ACCS(v6, e + 6);  ACCS(v7, e + 7);
            ACCS(v8, e + 8);  ACCS(v9, e + 9);  ACCS(vA, e + 10); ACCS(vB, e + 11);
            ACCS(vC, e + 12); ACCS(vD, e + 13); ACCS(vE, e + 14); ACCS(vF, e + 15);
        }
        for (; e + 4 <= e4; e += 4) {
            const int4 sA = *(const int4*)(ssrc + e);
            float v0 = hin[(size_t)sA.x * Hd + lane];
            float v1 = hin[(size_t)sA.y * Hd + lane];
            float v2 = hin[(size_t)sA.z * Hd + lane];
            float v3 = hin[(size_t)sA.w * Hd + lane];
            ACCS(v0, e + 0); ACCS(v1, e + 1); ACCS(v2, e + 2); ACCS(v3, e + 3);
        }
        for (; e < e4; e++) {
            int s = rfl(ssrc[e]);
            float v = hin[(size_t)s * Hd + lane];
            ACCS(v, e);
        }
        aggR[((size_t)0 * Nn + n) * Hd + lane] = a0;   // means (inv folded)
        aggR[((size_t)1 * Nn + n) * Hd + lane] = a1;
        aggR[((size_t)2 * Nn + n) * Hd + lane] = a2;
        aggR[((size_t)3 * Nn + n) * Hd + lane] = a3;
    }
}

// ---- RGCN transform as tiled GEMM: out = relu(b + [hin|mean0..3] @ [Wroot;W]) ----
__global__ __launch_bounds__(256) void k_rgcn_gemm(
        const float* __restrict__ hin, const float* __restrict__ aggR,
        const float* __restrict__ W, const float* __restrict__ Wroot,
        const float* __restrict__ bias, float* __restrict__ hout) {
    __shared__ float As[64 * LDA];                  // 17 KB, padded rows
    __shared__ float Bs[64 * 64];                   // 16 KB
    int tid = threadIdx.x;
    int n0 = blockIdx.x * 64;
    int wv = tid >> 6, lane = tid & 63;
    int r = lane >> 4, c = lane & 15;
    int row_base = wv * 16 + 4 * r;                 // 4 consecutive A rows per lane
    float acc[4][4];
    #pragma unroll
    for (int i = 0; i < 4; i++)
        #pragma unroll
        for (int j = 0; j < 4; j++) acc[i][j] = 0.f;
    for (int p = 0; p < 5; p++) {
        const float* Bsrc = (p == 0) ? Wroot : (W + (size_t)(p - 1) * Hd * Hd);
        #pragma unroll
        for (int q = 0; q < 4; q++) {
            int idx = q * 256 + tid;                // 0..1023 float4 slots
            int arow = idx >> 4;
            int ac4 = idx & 15;
            int n = n0 + arow; if (n >= Nn) n = Nn - 1;
            const float* asrc = (p == 0) ? (hin + (size_t)n * Hd)
                                         : (aggR + ((size_t)(p - 1) * Nn + n) * Hd);
            *(float4*)&As[arow * LDA + ac4 * 4] = *(const float4*)(asrc + ac4 * 4);
            *(float4*)&Bs[idx * 4] = *(const float4*)(Bsrc + idx * 4);
        }
        __syncthreads();
        for (int k4 = 0; k4 < 64; k4 += 4) {
            float4 aa[4], bb[4];
            #pragma unroll
            for (int i = 0; i < 4; i++)
                aa[i] = *(float4*)&As[(row_base + i) * LDA + k4];
            #pragma unroll
            for (int kk = 0; kk < 4; kk++)
                bb[kk] = *(float4*)&Bs[(k4 + kk) * 64 + c * 4];
            #pragma unroll
            for (int i = 0; i < 4; i++) {
                acc[i][0] += aa[i].x * bb[0].x + aa[i].y * bb[1].x
                           + aa[i].z * bb[2].x + aa[i].w * bb[3].x;
                acc[i][1] += aa[i].x * bb[0].y + aa[i].y * bb[1].y
                           + aa[i].z * bb[2].y + aa[i].w * bb[3].y;
                acc[i][2] += aa[i].x * bb[0].z + aa[i].y * bb[1].z
                           + aa[i].z * bb[2].z + aa[i].w * bb[3].z;
                acc[i][3] += aa[i].x * bb[0].w + aa[i].y * bb[1].w
                           + aa[i].z * bb[2].w + aa[i].w * bb[3].w;
            }
        }
        __syncthreads();
    }
    float4 bj = *(const float4*)(bias + c * 4);
    #pragma unroll
    for (int i = 0; i < 4; i++) {
        int n = n0 + row_base + i;
        if (n < Nn) {
            float4 o;
            o.x = reluf(acc[i][0] + bj.x);
            o.y = reluf(acc[i][1] + bj.y);
            o.z = reluf(acc[i][2] + bj.z);
            o.w = reluf(acc[i][3] + bj.w);
            *(float4*)&hout[(size_t)n * Hd + c * 4] = o;
        }
    }
}

// ---- FUSED MFConv layer: 16-deep unrolled gather + degree-bucketed transform ----
// (R10 shape: per-wave weight streams from hot L2, no barrier, 4-aligned buckets.
//  R11's per-block LDS weight staging REGRESSED: occ 33%, +barrier — do not re-add.)
__global__ __launch_bounds__(256) void k_mf_fused(
        const float* __restrict__ hin, const int* __restrict__ off,
        const int* __restrict__ ssrc, const int* __restrict__ order,
        const float* __restrict__ Wl, const float* __restrict__ bl,
        const float* __restrict__ Wr, float* __restrict__ hout, int relu_out) {
    __shared__ float lds[4][4][Hd];                 // 4 KB: [wave][node][k]
    int tid = threadIdx.x;
    int wv = tid >> 6, lane = tid & 63;
    int slot0 = rfl(blockIdx.x * 16 + wv * 4);
    int ent[4];
    #pragma unroll
    for (int i = 0; i < 4; i++) ent[i] = rfl(order[slot0 + i]);
    int d = -1;
    #pragma unroll
    for (int i = 3; i >= 0; i--) if (ent[i] >= 0) d = ent[i] >> 20;
    if (d < 0) return;
    int n[4];
    #pragma unroll
    for (int i = 0; i < 4; i++) n[i] = (ent[i] >= 0) ? (ent[i] & 0xFFFFF) : 0;
    for (int i = 0; i < 4; i++) {
        int e0 = rfl(off[n[i] * Rr]);
        int e4 = rfl(off[n[i] * Rr + Rr]);
        float p0 = 0.f, p1 = 0.f, p2 = 0.f, p3 = 0.f;
        int e = e0;
        for (; e + 16 <= e4; e += 16) {
            const int4 sA = *(const int4*)(ssrc + e);
            const int4 sB = *(const int4*)(ssrc + e + 4);
            const int4 sC = *(const int4*)(ssrc + e + 8);
            const int4 sD = *(const int4*)(ssrc + e + 12);
            p0 += hin[(size_t)sA.x * Hd + lane] + hin[(size_t)sA.y * Hd + lane]
                + hin[(size_t)sA.z * Hd + lane] + hin[(size_t)sA.w * Hd + lane];
            p1 += hin[(size_t)sB.x * Hd + lane] + hin[(size_t)sB.y * Hd + lane]
                + hin[(size_t)sB.z * Hd + lane] + hin[(size_t)sB.w * Hd + lane];
            p2 += hin[(size_t)sC.x * Hd + lane] + hin[(size_t)sC.y * Hd + lane]
                + hin[(size_t)sC.z * Hd + lane] + hin[(size_t)sC.w * Hd + lane];
            p3 += hin[(size_t)sD.x * Hd + lane] + hin[(size_t)sD.y * Hd + lane]
                + hin[(size_t)sD.z * Hd + lane] + hin[(size_t)sD.w * Hd + lane];
        }
        for (; e + 4 <= e4; e += 4) {
            const int4 sA = *(const int4*)(ssrc + e);
            p0 += hin[(size_t)sA.x * Hd + lane] + hin[(size_t)sA.y * Hd + lane]
                + hin[(size_t)sA.z * Hd + lane] + hin[(size_t)sA.w * Hd + lane];
        }
        for (; e < e4; e++) {
            int s = rfl(ssrc[e]);
            p0 += hin[(size_t)s * Hd + lane];
        }
        lds[wv][i][lane] = (p0 + p1) + (p2 + p3);
    }
    const float* wl = Wl + (size_t)d * Hd * Hd;
    const float* wr = Wr + (size_t)d * Hd * Hd;
    float acc[4] = {0.f, 0.f, 0.f, 0.f};
    for (int kc = 0; kc < Hd; kc += 4) {
        float a0 = wl[(kc + 0) * Hd + lane];
        float a1 = wl[(kc + 1) * Hd + lane];
        float a2 = wl[(kc + 2) * Hd + lane];
        float a3 = wl[(kc + 3) * Hd + lane];
        float b0 = wr[(kc + 0) * Hd + lane];
        float b1 = wr[(kc + 1) * Hd + lane];
        float b2 = wr[(kc + 2) * Hd + lane];
        float b3 = wr[(kc + 3) * Hd + lane];
        #pragma unroll
        for (int i = 0; i < 4; i++) {
            const float4 av = *(const float4*)(&lds[wv][i][kc]);
            const float4 hv = *(const float4*)(hin + (size_t)n[i] * Hd + kc);
            acc[i] += av.x * a0 + av.y * a1 + av.z * a2 + av.w * a3
                    + hv.x * b0 + hv.y * b1 + hv.z * b2 + hv.w * b3;
        }
    }
    float bb = bl[d * Hd + lane];
    #pragma unroll
    for (int i = 0; i < 4; i++)
        if (ent[i] >= 0) {
            float v = acc[i] + bb;
            hout[(size_t)n[i] * Hd + lane] = relu_out ? reluf(v) : v;
        }
}

// ---- global add pool (batch_idx is sorted -> mostly single fused atomic) ----
__global__ void k_pool(const float* __restrict__ h, const int* __restrict__ batch,
                       float* __restrict__ g) {
    int wave = rfl((blockIdx.x * 256 + threadIdx.x) >> 6);
    int lane = threadIdx.x & 63;
    int n0 = wave * 4;
    if (n0 >= Nn) return;
    int b0 = batch[n0], b1 = batch[n0 + 1], b2 = batch[n0 + 2], b3 = batch[n0 + 3];
    float v0 = h[(size_t)n0 * Hd + lane];
    float v1 = h[(size_t)(n0 + 1) * Hd + lane];
    float v2 = h[(size_t)(n0 + 2) * Hd + lane];
    float v3 = h[(size_t)(n0 + 3) * Hd + lane];
    if (b0 == b1 && b0 == b2 && b0 == b3) {
        unsafeAtomicAdd(&g[(size_t)b0 * Hd + lane], v0 + v1 + v2 + v3);
    } else {
        unsafeAtomicAdd(&g[(size_t)b0 * Hd + lane], v0);
        unsafeAtomicAdd(&g[(size_t)b1 * Hd + lane], v1);
        unsafeAtomicAdd(&g[(size_t)b2 * Hd + lane], v2);
        unsafeAtomicAdd(&g[(size_t)b3 * Hd + lane], v3);
    }
}

// ---- head: relu(g@lin1+b1)@lin2+b2, one wave per graph ----
__global__ void k_head(const float* __restrict__ g, const float* __restrict__ w1,
                       const float* __restrict__ b1, const float* __restrict__ w2,
                       const float* __restrict__ b2, float* __restrict__ out) {
    __shared__ float t[4][Hd];
    int wv = threadIdx.x >> 6;
    int lane = threadIdx.x & 63;
    int gi = blockIdx.x * 4 + wv;
    float acc = b1[lane];
    for (int k = 0; k < Hd; k++) acc += g[(size_t)gi * Hd + k] * w1[k * Hd + lane];
    t[wv][lane] = reluf(acc);
    __syncthreads();
    if (lane < Od) {
        float o = b2[lane];
        for (int k = 0; k < Hd; k++) o += t[wv][k] * w2[k * Od + lane];
        out[(size_t)gi * Od + lane] = o;
    }
}

extern "C" void kernel_launch(void* const* d_in, const int* in_sizes, int n_in,
                              void* d_out, int out_size, void* d_ws, size_t ws_size,
                              hipStream_t stream) {
    const float* x      = (const float*)d_in[0];
    const float* ea     = (const float*)d_in[1];
    const int*   eidx   = (const int*)d_in[2];
    const int*   batch  = (const int*)d_in[3];
    const float* emb    = (const float*)d_in[4];
    const float* lin1_w = (const float*)d_in[5];
    const float* lin1_b = (const float*)d_in[6];
    const float* lin2_w = (const float*)d_in[7];
    const float* lin2_b = (const float*)d_in[8];
    const float* rgcn_w[2]    = {(const float*)d_in[9],  (const float*)d_in[15]};
    const float* rgcn_root[2] = {(const float*)d_in[10], (const float*)d_in[16]};
    const float* rgcn_b[2]    = {(const float*)d_in[11], (const float*)d_in[17]};
    const float* mf_wl[2]     = {(const float*)d_in[12], (const float*)d_in[18]};
    const float* mf_bl[2]     = {(const float*)d_in[13], (const float*)d_in[19]};
    const float* mf_wr[2]     = {(const float*)d_in[14], (const float*)d_in[20]};

    char* p = (char*)d_ws;
    float* h0   = (float*)p; p += sizeof(float) * (size_t)Nn * Hd;
    float* h1   = (float*)p; p += sizeof(float) * (size_t)Nn * Hd;
    float* aggR = (float*)p; p += sizeof(float) * (size_t)Rr * Nn * Hd;
    float* gbuf = (float*)p; p += sizeof(float) * (size_t)Ng * Hd;
    int* seg    = (int*)p;   p += sizeof(int) * (size_t)Ne;
    int* rank   = (int*)p;   p += sizeof(int) * (size_t)Ne;
    int* ssrc   = (int*)p;   p += sizeof(int) * (size_t)Ne;
    int* cnt    = (int*)p;   p += sizeof(int) * (size_t)NSEG;   // contiguous with bcnt/bfill
    int* bcnt   = (int*)p;   p += sizeof(int) * 16;
    int* bfill  = (int*)p;   p += sizeof(int) * 16;
    int* off    = (int*)p;   p += sizeof(int) * (size_t)(NSEG + 1);
    int* bsum   = (int*)p;   p += sizeof(int) * 1024;
    int* bbase  = (int*)p;   p += sizeof(int) * 16;
    int* order  = (int*)p;   p += sizeof(int) * (size_t)ORDER_SZ;

    hipMemsetAsync(cnt, 0, sizeof(int) * ((size_t)NSEG + 32), stream);
    hipMemsetAsync(gbuf, 0, sizeof(float) * (size_t)Ng * Hd, stream);

    k_rel_seg<<<Ne / 256, 256, 0, stream>>>((const float4*)ea, eidx, seg, rank, cnt);
    k_scan1<<<SCAN_BLK, 256, 0, stream>>>(cnt, off, bsum, bcnt);
    k_scan2<<<1, 1024, 0, stream>>>(bsum, bcnt, bbase, order);
    k_scan3<<<SCAN_BLK, 256, 0, stream>>>(off, bsum);
    k_scatter<<<Ne / 256, 256, 0, stream>>>(eidx, seg, rank, off, ssrc);
    k_embed<<<Nn / 4, 256, 0, stream>>>(x, emb, h0);
    k_bucket_scatter<<<(Nn + 255) / 256, 256, 0, stream>>>((const int4*)cnt, bbase, bfill, order);

    float* hin = h0;
    float* hout = h1;
    for (int b = 0; b < 2; b++) {
        k_rgcn_gather<<<NB_RG, 256, 0, stream>>>(hin, off, ssrc, aggR);
        k_rgcn_gemm<<<NB_GEMM, 256, 0, stream>>>(hin, aggR, rgcn_w[b], rgcn_root[b],
                                                 rgcn_b[b], hout);
        k_mf_fused<<<NB_MF, 256, 0, stream>>>(hout, off, ssrc, order, mf_wl[b],
                                              mf_bl[b], mf_wr[b], hin, b == 0 ? 1 : 0);
        // block output is back in hin for the next block (relu'd for b=0, raw for b=1)
    }
    k_pool<<<Nn / 16, 256, 0, stream>>>(hin, batch, gbuf);
    k_head<<<Ng / 4, 256, 0, stream>>>(gbuf, lin1_w, lin1_b, lin2_w, lin2_b, (float*)d_out);
}

// Round 13
// 445.166 us; speedup vs baseline: 1.0841x; 1.0185x over previous
//
#include <hip/hip_runtime.h>
#include <cstdint>
#include <cstddef>

#define Nn 50000
#define Ne 800000
#define Ng 1024
#define NFd 32
#define Rr 4
#define Hd 64
#define Od 16
#define MAXD 10
#define NSEG (Nn * Rr)
#define SCAN_BLK ((NSEG + 255) / 256)
#define ORDER_SZ (Nn + 48)                 // buckets padded to x4: max 11*3 pad
#define NB_MF ((ORDER_SZ + 15) / 16)       // block = 4 waves x 4 slots
#define NB_RG (Nn / 16)                    // block = 4 waves x 4 nodes
#define NB_GEMM ((Nn + 63) / 64)           // 782 blocks of 64 nodes
#define NB_RELSEG (Ne / 256)               // 3125 edge blocks
#define NB_EMBED (Nn / 4)                  // 12500 embed blocks
#define LDA 68                             // padded A leading dim (bank-conflict-free)

__device__ __forceinline__ float reluf(float v) { return v > 0.f ? v : 0.f; }
__device__ __forceinline__ int rfl(int v) { return __builtin_amdgcn_readfirstlane(v); }

// ---- FUSED: per-edge relation argmax/histogram/rank  +  embedding lookup ----
// Independent work merged into one grid so embed hides under atomic stalls.
__global__ void k_rel_emb(const float4* __restrict__ ea, const int* __restrict__ eidx,
                          int* __restrict__ seg, int* __restrict__ rank,
                          int* __restrict__ cnt,
                          const float* __restrict__ x, const float* __restrict__ emb,
                          float* __restrict__ h) {
    if (blockIdx.x < NB_RELSEG) {
        int e = blockIdx.x * 256 + threadIdx.x;     // grid sized exactly: e < Ne
        float4 a = ea[e];
        int bi = 0; float bv = a.x;
        if (a.y > bv) { bv = a.y; bi = 1; }
        if (a.z > bv) { bv = a.z; bi = 2; }
        if (a.w > bv) { bv = a.w; bi = 3; }
        int s = eidx[Ne + e] * Rr + bi;
        seg[e] = s;
        rank[e] = atomicAdd(&cnt[s], 1);
    } else {
        int wave = ((blockIdx.x - NB_RELSEG) * 256 + threadIdx.x) >> 6;  // < Nn
        int lane = threadIdx.x & 63;
        float v = (lane < NFd) ? x[(size_t)wave * NFd + lane] : -1e30f;
        int idx = lane;
        #pragma unroll
        for (int off = 16; off >= 1; off >>= 1) {
            float ov = __shfl_down(v, off);
            int oi = __shfl_down(idx, off);
            if (ov > v || (ov == v && oi < idx)) { v = ov; idx = oi; }
        }
        idx = __shfl(idx, 0);
        h[(size_t)wave * Hd + lane] = reluf(emb[(size_t)idx * Hd + lane]);
    }
}

// ---- scan level 1 + fused degree histogram (deg(n) = sum of its 4 cnt entries) ----
__global__ void k_scan1(const int* __restrict__ cnt, int* __restrict__ off,
                        int* __restrict__ bsum, int* __restrict__ bcnt) {
    __shared__ int s[256];
    __shared__ int hist[16];
    int t = threadIdx.x;
    if (t < 16) hist[t] = 0;
    int idx = blockIdx.x * 256 + t;
    int v = (idx < NSEG) ? cnt[idx] : 0;
    s[t] = v;
    __syncthreads();
    if ((t & 3) == 0 && idx < NSEG) {
        int dsum = s[t] + s[t + 1] + s[t + 2] + s[t + 3];
        atomicAdd(&hist[min(dsum, MAXD)], 1);
    }
    #pragma unroll
    for (int o = 1; o < 256; o <<= 1) {
        int x = (t >= o) ? s[t - o] : 0;
        __syncthreads();
        s[t] += x;
        __syncthreads();
    }
    if (idx < NSEG) off[idx] = s[t] - v;            // exclusive
    if (t == 255) bsum[blockIdx.x] = s[255];
    if (t < 16) {
        int h = hist[t];
        if (h > 0) atomicAdd(&bcnt[t], h);
    }
}

// ---- scan level 2 + fused bucket prefix (4-aligned) + order pad-slot writes ----
__global__ void k_scan2(int* __restrict__ bsum, const int* __restrict__ bcnt,
                        int* __restrict__ bbase, int* __restrict__ order) {
    __shared__ int s[1024];
    int t = threadIdx.x;
    int v = (t < SCAN_BLK) ? bsum[t] : 0;
    s[t] = v;
    __syncthreads();
    #pragma unroll
    for (int o = 1; o < 1024; o <<= 1) {
        int x = (t >= o) ? s[t - o] : 0;
        __syncthreads();
        s[t] += x;
        __syncthreads();
    }
    if (t < SCAN_BLK) bsum[t] = s[t] - v;           // exclusive block bases
    if (t == 0) {
        int run = 0;
        for (int d = 0; d <= MAXD; d++) {
            int c = bcnt[d];
            bbase[d] = run;
            int pad = (c + 3) & ~3;
            for (int i = c; i < pad; i++) order[run + i] = -1;
            run += pad;
        }
        for (int i = run; i < ORDER_SZ; i++) order[i] = -1;
    }
}

// ---- FUSED: scan level 3 (final off)  +  degree-bucket scatter (cnt-based) ----
__global__ void k_scan3_bucket(int* __restrict__ off, const int* __restrict__ bsum,
                               const int4* __restrict__ cnt4, const int* __restrict__ bbase,
                               int* __restrict__ bfill, int* __restrict__ order) {
    __shared__ int hist[16];
    __shared__ int base[16];
    int t = threadIdx.x;
    if (t < 16) hist[t] = 0;
    __syncthreads();
    int idx = blockIdx.x * 256 + t;
    if (idx == 0) off[NSEG] = Ne;
    if (idx < NSEG) off[idx] = off[idx] + bsum[blockIdx.x];
    int d = 0, rk = 0;
    bool valid = (idx < Nn);
    if (valid) {
        int4 c = cnt4[idx];
        d = min(c.x + c.y + c.z + c.w, MAXD);
        rk = atomicAdd(&hist[d], 1);
    }
    __syncthreads();
    if (t < 16) {
        int h = hist[t];
        base[t] = (h > 0) ? atomicAdd(&bfill[t], h) : 0;
    }
    __syncthreads();
    if (valid) order[bbase[d] + base[d] + rk] = idx | (d << 20);
}

// ---- scatter edges into segment-sorted order: NO atomics (rank precomputed) ----
__global__ void k_scatter(const int* __restrict__ eidx, const int* __restrict__ seg,
                          const int* __restrict__ rank, const int* __restrict__ off,
                          int* __restrict__ sorted_src) {
    int e = blockIdx.x * 256 + threadIdx.x;
    if (e >= Ne) return;
    int pos = off[seg[e]] + rank[e];
    sorted_src[pos] = eidx[e];
}

// classify edge ee via wave-uniform boundaries -> 4 uniform scalar scales
#define ACCS(v, ee)  {                                      \
    int rr = ((ee) >= e1) + ((ee) >= e2) + ((ee) >= e3);    \
    float s0 = (rr == 0) ? i0 : 0.f;                        \
    float s1 = (rr == 1) ? i1 : 0.f;                        \
    float s2 = (rr == 2) ? i2 : 0.f;                        \
    float s3 = (rr == 3) ? i3 : 0.f;                        \
    a0 = fmaf(s0, (v), a0);                                 \
    a1 = fmaf(s1, (v), a1);                                 \
    a2 = fmaf(s2, (v), a2);                                 \
    a3 = fmaf(s3, (v), a3); }

// ---- RGCN gather: 16-deep unrolled gather -> rel-major means aggR[r][n][64] ----
__global__ __launch_bounds__(256) void k_rgcn_gather(
        const float* __restrict__ hin, const int* __restrict__ off,
        const int* __restrict__ ssrc, float* __restrict__ aggR) {
    int tid = threadIdx.x;
    int wv = tid >> 6, lane = tid & 63;
    int wave = rfl(blockIdx.x * 4 + wv);
    int n0 = wave * 4;
    for (int i = 0; i < 4; i++) {
        int n = n0 + i;
        int nb = n * Rr;
        int e0 = rfl(off[nb]);
        int e1 = rfl(off[nb + 1]);
        int e2 = rfl(off[nb + 2]);
        int e3 = rfl(off[nb + 3]);
        int e4 = rfl(off[nb + 4]);
        float i0 = (e1 > e0) ? 1.f / (float)(e1 - e0) : 0.f;
        float i1 = (e2 > e1) ? 1.f / (float)(e2 - e1) : 0.f;
        float i2 = (e3 > e2) ? 1.f / (float)(e3 - e2) : 0.f;
        float i3 = (e4 > e3) ? 1.f / (float)(e4 - e3) : 0.f;
        float a0 = 0.f, a1 = 0.f, a2 = 0.f, a3 = 0.f;
        int e = e0;
        for (; e + 16 <= e4; e += 16) {             // 16 loads in flight
            const int4 sA = *(const int4*)(ssrc + e);
            const int4 sB = *(const int4*)(ssrc + e + 4);
            const int4 sC = *(const int4*)(ssrc + e + 8);
            const int4 sD = *(const int4*)(ssrc + e + 12);
            float v0 = hin[(size_t)sA.x * Hd + lane];
            float v1 = hin[(size_t)sA.y * Hd + lane];
            float v2 = hin[(size_t)sA.z * Hd + lane];
            float v3 = hin[(size_t)sA.w * Hd + lane];
            float v4 = hin[(size_t)sB.x * Hd + lane];
            float v5 = hin[(size_t)sB.y * Hd + lane];
            float v6 = hin[(size_t)sB.z * Hd + lane];
            float v7 = hin[(size_t)sB.w * Hd + lane];
            float v8 = hin[(size_t)sC.x * Hd + lane];
            float v9 = hin[(size_t)sC.y * Hd + lane];
            float vA = hin[(size_t)sC.z * Hd + lane];
            float vB = hin[(size_t)sC.w * Hd + lane];
            float vC = hin[(size_t)sD.x * Hd + lane];
            float vD = hin[(size_t)sD.y * Hd + lane];
            float vE = hin[(size_t)sD.z * Hd + lane];
            float vF = hin[(size_t)sD.w * Hd + lane];
            ACCS(v0, e + 0);  ACCS(v1, e + 1);  ACCS(v2, e + 2);  ACCS(v3, e + 3);
            ACCS(v4, e + 4);  ACCS(v5, e + 5);  ACCS(v6, e + 6);  ACCS(v7, e + 7);
            ACCS(v8, e + 8);  ACCS(v9, e + 9);  ACCS(vA, e + 10); ACCS(vB, e + 11);
            ACCS(vC, e + 12); ACCS(vD, e + 13); ACCS(vE, e + 14); ACCS(vF, e + 15);
        }
        for (; e + 4 <= e4; e += 4) {
            const int4 sA = *(const int4*)(ssrc + e);
            float v0 = hin[(size_t)sA.x * Hd + lane];
            float v1 = hin[(size_t)sA.y * Hd + lane];
            float v2 = hin[(size_t)sA.z * Hd + lane];
            float v3 = hin[(size_t)sA.w * Hd + lane];
            ACCS(v0, e + 0); ACCS(v1, e + 1); ACCS(v2, e + 2); ACCS(v3, e + 3);
        }
        for (; e < e4; e++) {
            int s = rfl(ssrc[e]);
            float v = hin[(size_t)s * Hd + lane];
            ACCS(v, e);
        }
        aggR[((size_t)0 * Nn + n) * Hd + lane] = a0;   // means (inv folded)
        aggR[((size_t)1 * Nn + n) * Hd + lane] = a1;
        aggR[((size_t)2 * Nn + n) * Hd + lane] = a2;
        aggR[((size_t)3 * Nn + n) * Hd + lane] = a3;
    }
}

// ---- RGCN transform as tiled GEMM: out = relu(b + [hin|mean0..3] @ [Wroot;W]) ----
__global__ __launch_bounds__(256) void k_rgcn_gemm(
        const float* __restrict__ hin, const float* __restrict__ aggR,
        const float* __restrict__ W, const float* __restrict__ Wroot,
        const float* __restrict__ bias, float* __restrict__ hout) {
    __shared__ float As[64 * LDA];                  // 17 KB, padded rows
    __shared__ float Bs[64 * 64];                   // 16 KB
    int tid = threadIdx.x;
    int n0 = blockIdx.x * 64;
    int wv = tid >> 6, lane = tid & 63;
    int r = lane >> 4, c = lane & 15;
    int row_base = wv * 16 + 4 * r;                 // 4 consecutive A rows per lane
    float acc[4][4];
    #pragma unroll
    for (int i = 0; i < 4; i++)
        #pragma unroll
        for (int j = 0; j < 4; j++) acc[i][j] = 0.f;
    for (int p = 0; p < 5; p++) {
        const float* Bsrc = (p == 0) ? Wroot : (W + (size_t)(p - 1) * Hd * Hd);
        #pragma unroll
        for (int q = 0; q < 4; q++) {
            int idx = q * 256 + tid;                // 0..1023 float4 slots
            int arow = idx >> 4;
            int ac4 = idx & 15;
            int n = n0 + arow; if (n >= Nn) n = Nn - 1;
            const float* asrc = (p == 0) ? (hin + (size_t)n * Hd)
                                         : (aggR + ((size_t)(p - 1) * Nn + n) * Hd);
            *(float4*)&As[arow * LDA + ac4 * 4] = *(const float4*)(asrc + ac4 * 4);
            *(float4*)&Bs[idx * 4] = *(const float4*)(Bsrc + idx * 4);
        }
        __syncthreads();
        for (int k4 = 0; k4 < 64; k4 += 4) {
            float4 aa[4], bb[4];
            #pragma unroll
            for (int i = 0; i < 4; i++)
                aa[i] = *(float4*)&As[(row_base + i) * LDA + k4];
            #pragma unroll
            for (int kk = 0; kk < 4; kk++)
                bb[kk] = *(float4*)&Bs[(k4 + kk) * 64 + c * 4];
            #pragma unroll
            for (int i = 0; i < 4; i++) {
                acc[i][0] += aa[i].x * bb[0].x + aa[i].y * bb[1].x
                           + aa[i].z * bb[2].x + aa[i].w * bb[3].x;
                acc[i][1] += aa[i].x * bb[0].y + aa[i].y * bb[1].y
                           + aa[i].z * bb[2].y + aa[i].w * bb[3].y;
                acc[i][2] += aa[i].x * bb[0].z + aa[i].y * bb[1].z
                           + aa[i].z * bb[2].z + aa[i].w * bb[3].z;
                acc[i][3] += aa[i].x * bb[0].w + aa[i].y * bb[1].w
                           + aa[i].z * bb[2].w + aa[i].w * bb[3].w;
            }
        }
        __syncthreads();
    }
    float4 bj = *(const float4*)(bias + c * 4);
    #pragma unroll
    for (int i = 0; i < 4; i++) {
        int n = n0 + row_base + i;
        if (n < Nn) {
            float4 o;
            o.x = reluf(acc[i][0] + bj.x);
            o.y = reluf(acc[i][1] + bj.y);
            o.z = reluf(acc[i][2] + bj.z);
            o.w = reluf(acc[i][3] + bj.w);
            *(float4*)&hout[(size_t)n * Hd + c * 4] = o;
        }
    }
}

// ---- FUSED MFConv layer: 16-deep unrolled gather + degree-bucketed transform ----
// (R10 shape: per-wave weight streams from hot L2, no barrier, 4-aligned buckets.
//  R11's per-block LDS weight staging REGRESSED: occ 33%, +barrier — do not re-add.)
__global__ __launch_bounds__(256) void k_mf_fused(
        const float* __restrict__ hin, const int* __restrict__ off,
        const int* __restrict__ ssrc, const int* __restrict__ order,
        const float* __restrict__ Wl, const float* __restrict__ bl,
        const float* __restrict__ Wr, float* __restrict__ hout, int relu_out) {
    __shared__ float lds[4][4][Hd];                 // 4 KB: [wave][node][k]
    int tid = threadIdx.x;
    int wv = tid >> 6, lane = tid & 63;
    int slot0 = rfl(blockIdx.x * 16 + wv * 4);
    int ent[4];
    #pragma unroll
    for (int i = 0; i < 4; i++) ent[i] = rfl(order[slot0 + i]);
    int d = -1;
    #pragma unroll
    for (int i = 3; i >= 0; i--) if (ent[i] >= 0) d = ent[i] >> 20;
    if (d < 0) return;
    int n[4];
    #pragma unroll
    for (int i = 0; i < 4; i++) n[i] = (ent[i] >= 0) ? (ent[i] & 0xFFFFF) : 0;
    for (int i = 0; i < 4; i++) {
        int e0 = rfl(off[n[i] * Rr]);
        int e4 = rfl(off[n[i] * Rr + Rr]);
        float p0 = 0.f, p1 = 0.f, p2 = 0.f, p3 = 0.f;
        int e = e0;
        for (; e + 16 <= e4; e += 16) {
            const int4 sA = *(const int4*)(ssrc + e);
            const int4 sB = *(const int4*)(ssrc + e + 4);
            const int4 sC = *(const int4*)(ssrc + e + 8);
            const int4 sD = *(const int4*)(ssrc + e + 12);
            p0 += hin[(size_t)sA.x * Hd + lane] + hin[(size_t)sA.y * Hd + lane]
                + hin[(size_t)sA.z * Hd + lane] + hin[(size_t)sA.w * Hd + lane];
            p1 += hin[(size_t)sB.x * Hd + lane] + hin[(size_t)sB.y * Hd + lane]
                + hin[(size_t)sB.z * Hd + lane] + hin[(size_t)sB.w * Hd + lane];
            p2 += hin[(size_t)sC.x * Hd + lane] + hin[(size_t)sC.y * Hd + lane]
                + hin[(size_t)sC.z * Hd + lane] + hin[(size_t)sC.w * Hd + lane];
            p3 += hin[(size_t)sD.x * Hd + lane] + hin[(size_t)sD.y * Hd + lane]
                + hin[(size_t)sD.z * Hd + lane] + hin[(size_t)sD.w * Hd + lane];
        }
        for (; e + 4 <= e4; e += 4) {
            const int4 sA = *(const int4*)(ssrc + e);
            p0 += hin[(size_t)sA.x * Hd + lane] + hin[(size_t)sA.y * Hd + lane]
                + hin[(size_t)sA.z * Hd + lane] + hin[(size_t)sA.w * Hd + lane];
        }
        for (; e < e4; e++) {
            int s = rfl(ssrc[e]);
            p0 += hin[(size_t)s * Hd + lane];
        }
        lds[wv][i][lane] = (p0 + p1) + (p2 + p3);
    }
    const float* wl = Wl + (size_t)d * Hd * Hd;
    const float* wr = Wr + (size_t)d * Hd * Hd;
    float acc[4] = {0.f, 0.f, 0.f, 0.f};
    for (int kc = 0; kc < Hd; kc += 4) {
        float a0 = wl[(kc + 0) * Hd + lane];
        float a1 = wl[(kc + 1) * Hd + lane];
        float a2 = wl[(kc + 2) * Hd + lane];
        float a3 = wl[(kc + 3) * Hd + lane];
        float b0 = wr[(kc + 0) * Hd + lane];
        float b1 = wr[(kc + 1) * Hd + lane];
        float b2 = wr[(kc + 2) * Hd + lane];
        float b3 = wr[(kc + 3) * Hd + lane];
        #pragma unroll
        for (int i = 0; i < 4; i++) {
            const float4 av = *(const float4*)(&lds[wv][i][kc]);
            const float4 hv = *(const float4*)(hin + (size_t)n[i] * Hd + kc);
            acc[i] += av.x * a0 + av.y * a1 + av.z * a2 + av.w * a3
                    + hv.x * b0 + hv.y * b1 + hv.z * b2 + hv.w * b3;
        }
    }
    float bb = bl[d * Hd + lane];
    #pragma unroll
    for (int i = 0; i < 4; i++)
        if (ent[i] >= 0) {
            float v = acc[i] + bb;
            hout[(size_t)n[i] * Hd + lane] = relu_out ? reluf(v) : v;
        }
}

// ---- global add pool (batch_idx is sorted -> mostly single fused atomic) ----
__global__ void k_pool(const float* __restrict__ h, const int* __restrict__ batch,
                       float* __restrict__ g) {
    int wave = rfl((blockIdx.x * 256 + threadIdx.x) >> 6);
    int lane = threadIdx.x & 63;
    int n0 = wave * 4;
    if (n0 >= Nn) return;
    int b0 = batch[n0], b1 = batch[n0 + 1], b2 = batch[n0 + 2], b3 = batch[n0 + 3];
    float v0 = h[(size_t)n0 * Hd + lane];
    float v1 = h[(size_t)(n0 + 1) * Hd + lane];
    float v2 = h[(size_t)(n0 + 2) * Hd + lane];
    float v3 = h[(size_t)(n0 + 3) * Hd + lane];
    if (b0 == b1 && b0 == b2 && b0 == b3) {
        unsafeAtomicAdd(&g[(size_t)b0 * Hd + lane], v0 + v1 + v2 + v3);
    } else {
        unsafeAtomicAdd(&g[(size_t)b0 * Hd + lane], v0);
        unsafeAtomicAdd(&g[(size_t)b1 * Hd + lane], v1);
        unsafeAtomicAdd(&g[(size_t)b2 * Hd + lane], v2);
        unsafeAtomicAdd(&g[(size_t)b3 * Hd + lane], v3);
    }
}

// ---- head: relu(g@lin1+b1)@lin2+b2, one wave per graph ----
__global__ void k_head(const float* __restrict__ g, const float* __restrict__ w1,
                       const float* __restrict__ b1, const float* __restrict__ w2,
                       const float* __restrict__ b2, float* __restrict__ out) {
    __shared__ float t[4][Hd];
    int wv = threadIdx.x >> 6;
    int lane = threadIdx.x & 63;
    int gi = blockIdx.x * 4 + wv;
    float acc = b1[lane];
    for (int k = 0; k < Hd; k++) acc += g[(size_t)gi * Hd + k] * w1[k * Hd + lane];
    t[wv][lane] = reluf(acc);
    __syncthreads();
    if (lane < Od) {
        float o = b2[lane];
        for (int k = 0; k < Hd; k++) o += t[wv][k] * w2[k * Od + lane];
        out[(size_t)gi * Od + lane] = o;
    }
}

extern "C" void kernel_launch(void* const* d_in, const int* in_sizes, int n_in,
                              void* d_out, int out_size, void* d_ws, size_t ws_size,
                              hipStream_t stream) {
    const float* x      = (const float*)d_in[0];
    const float* ea     = (const float*)d_in[1];
    const int*   eidx   = (const int*)d_in[2];
    const int*   batch  = (const int*)d_in[3];
    const float* emb    = (const float*)d_in[4];
    const float* lin1_w = (const float*)d_in[5];
    const float* lin1_b = (const float*)d_in[6];
    const float* lin2_w = (const float*)d_in[7];
    const float* lin2_b = (const float*)d_in[8];
    const float* rgcn_w[2]    = {(const float*)d_in[9],  (const float*)d_in[15]};
    const float* rgcn_root[2] = {(const float*)d_in[10], (const float*)d_in[16]};
    const float* rgcn_b[2]    = {(const float*)d_in[11], (const float*)d_in[17]};
    const float* mf_wl[2]     = {(const float*)d_in[12], (const float*)d_in[18]};
    const float* mf_bl[2]     = {(const float*)d_in[13], (const float*)d_in[19]};
    const float* mf_wr[2]     = {(const float*)d_in[14], (const float*)d_in[20]};

    char* p = (char*)d_ws;
    float* h0   = (float*)p; p += sizeof(float) * (size_t)Nn * Hd;
    float* h1   = (float*)p; p += sizeof(float) * (size_t)Nn * Hd;
    float* aggR = (float*)p; p += sizeof(float) * (size_t)Rr * Nn * Hd;
    float* gbuf = (float*)p; p += sizeof(float) * (size_t)Ng * Hd;
    int* seg    = (int*)p;   p += sizeof(int) * (size_t)Ne;
    int* rank   = (int*)p;   p += sizeof(int) * (size_t)Ne;
    int* ssrc   = (int*)p;   p += sizeof(int) * (size_t)Ne;
    int* cnt    = (int*)p;   p += sizeof(int) * (size_t)NSEG;   // contiguous with bcnt/bfill
    int* bcnt   = (int*)p;   p += sizeof(int) * 16;
    int* bfill  = (int*)p;   p += sizeof(int) * 16;
    int* off    = (int*)p;   p += sizeof(int) * (size_t)(NSEG + 1);
    int* bsum   = (int*)p;   p += sizeof(int) * 1024;
    int* bbase  = (int*)p;   p += sizeof(int) * 16;
    int* order  = (int*)p;   p += sizeof(int) * (size_t)ORDER_SZ;

    hipMemsetAsync(cnt, 0, sizeof(int) * ((size_t)NSEG + 32), stream);
    hipMemsetAsync(gbuf, 0, sizeof(float) * (size_t)Ng * Hd, stream);

    k_rel_emb<<<NB_RELSEG + NB_EMBED, 256, 0, stream>>>((const float4*)ea, eidx, seg, rank,
                                                        cnt, x, emb, h0);
    k_scan1<<<SCAN_BLK, 256, 0, stream>>>(cnt, off, bsum, bcnt);
    k_scan2<<<1, 1024, 0, stream>>>(bsum, bcnt, bbase, order);
    k_scan3_bucket<<<SCAN_BLK, 256, 0, stream>>>(off, bsum, (const int4*)cnt, bbase,
                                                 bfill, order);
    k_scatter<<<Ne / 256, 256, 0, stream>>>(eidx, seg, rank, off, ssrc);

    float* hin = h0;
    float* hout = h1;
    for (int b = 0; b < 2; b++) {
        k_rgcn_gather<<<NB_RG, 256, 0, stream>>>(hin, off, ssrc, aggR);
        k_rgcn_gemm<<<NB_GEMM, 256, 0, stream>>>(hin, aggR, rgcn_w[b], rgcn_root[b],
                                                 rgcn_b[b], hout);
        k_mf_fused<<<NB_MF, 256, 0, stream>>>(hout, off, ssrc, order, mf_wl[b],
                                              mf_bl[b], mf_wr[b], hin, b == 0 ? 1 : 0);
        // block output is back in hin for the next block (relu'd for b=0, raw for b=1)
    }
    k_pool<<<Nn / 16, 256, 0, stream>>>(hin, batch, gbuf);
    k_head<<<Ng / 4, 256, 0, stream>>>(gbuf, lin1_w, lin1_b, lin2_w, lin2_b, (float*)d_out);
}

// Round 14
// 433.576 us; speedup vs baseline: 1.1131x; 1.0267x over previous
//
#include <hip/hip_runtime.h>
#include <hip/hip_fp16.h>
#include <cstdint>
#include <cstddef>

#define Nn 50000
#define Ne 800000
#define Ng 1024
#define NFd 32
#define Rr 4
#define Hd 64
#define Od 16
#define MAXD 10
#define NSEG (Nn * Rr)
#define SCAN_BLK ((NSEG + 255) / 256)
#define ORDER_SZ (Nn + 48)                 // buckets padded to x4: max 11*3 pad
#define NB_MF ((ORDER_SZ + 15) / 16)       // block = 4 waves x 4 slots
#define NB_RG (Nn / 16)                    // block = 4 waves x 4 nodes
#define NB_GEMM ((Nn + 63) / 64)           // 782 blocks of 64 nodes
#define NB_RELSEG (Ne / 256)               // 3125 edge blocks
#define NB_EMBED (Nn / 4)                  // 12500 embed blocks
#define LDA 68                             // padded A leading dim (bank-conflict-free)

__device__ __forceinline__ float reluf(float v) { return v > 0.f ? v : 0.f; }
__device__ __forceinline__ int rfl(int v) { return __builtin_amdgcn_readfirstlane(v); }

// ---- FUSED: per-edge relation argmax/histogram/rank  +  embedding lookup ----
// Embed writes fp32 h (root/transform path) + fp16 shadow (gather path).
__global__ void k_rel_emb(const float4* __restrict__ ea, const int* __restrict__ eidx,
                          int* __restrict__ seg, int* __restrict__ rank,
                          int* __restrict__ cnt,
                          const float* __restrict__ x, const float* __restrict__ emb,
                          float* __restrict__ h, __half* __restrict__ h16) {
    if (blockIdx.x < NB_RELSEG) {
        int e = blockIdx.x * 256 + threadIdx.x;     // grid sized exactly: e < Ne
        float4 a = ea[e];
        int bi = 0; float bv = a.x;
        if (a.y > bv) { bv = a.y; bi = 1; }
        if (a.z > bv) { bv = a.z; bi = 2; }
        if (a.w > bv) { bv = a.w; bi = 3; }
        int s = eidx[Ne + e] * Rr + bi;
        seg[e] = s;
        rank[e] = atomicAdd(&cnt[s], 1);
    } else {
        int wave = ((blockIdx.x - NB_RELSEG) * 256 + threadIdx.x) >> 6;  // < Nn
        int lane = threadIdx.x & 63;
        float v = (lane < NFd) ? x[(size_t)wave * NFd + lane] : -1e30f;
        int idx = lane;
        #pragma unroll
        for (int off = 16; off >= 1; off >>= 1) {
            float ov = __shfl_down(v, off);
            int oi = __shfl_down(idx, off);
            if (ov > v || (ov == v && oi < idx)) { v = ov; idx = oi; }
        }
        idx = __shfl(idx, 0);
        float hv = reluf(emb[(size_t)idx * Hd + lane]);
        h[(size_t)wave * Hd + lane] = hv;
        h16[(size_t)wave * Hd + lane] = __float2half(hv);
    }
}

// ---- scan level 1 + fused degree histogram (deg(n) = sum of its 4 cnt entries) ----
__global__ void k_scan1(const int* __restrict__ cnt, int* __restrict__ off,
                        int* __restrict__ bsum, int* __restrict__ bcnt) {
    __shared__ int s[256];
    __shared__ int hist[16];
    int t = threadIdx.x;
    if (t < 16) hist[t] = 0;
    int idx = blockIdx.x * 256 + t;
    int v = (idx < NSEG) ? cnt[idx] : 0;
    s[t] = v;
    __syncthreads();
    if ((t & 3) == 0 && idx < NSEG) {
        int dsum = s[t] + s[t + 1] + s[t + 2] + s[t + 3];
        atomicAdd(&hist[min(dsum, MAXD)], 1);
    }
    #pragma unroll
    for (int o = 1; o < 256; o <<= 1) {
        int x = (t >= o) ? s[t - o] : 0;
        __syncthreads();
        s[t] += x;
        __syncthreads();
    }
    if (idx < NSEG) off[idx] = s[t] - v;            // exclusive
    if (t == 255) bsum[blockIdx.x] = s[255];
    if (t < 16) {
        int h = hist[t];
        if (h > 0) atomicAdd(&bcnt[t], h);
    }
}

// ---- scan level 2 + fused bucket prefix (4-aligned) + order pad-slot writes ----
__global__ void k_scan2(int* __restrict__ bsum, const int* __restrict__ bcnt,
                        int* __restrict__ bbase, int* __restrict__ order) {
    __shared__ int s[1024];
    int t = threadIdx.x;
    int v = (t < SCAN_BLK) ? bsum[t] : 0;
    s[t] = v;
    __syncthreads();
    #pragma unroll
    for (int o = 1; o < 1024; o <<= 1) {
        int x = (t >= o) ? s[t - o] : 0;
        __syncthreads();
        s[t] += x;
        __syncthreads();
    }
    if (t < SCAN_BLK) bsum[t] = s[t] - v;           // exclusive block bases
    if (t == 0) {
        int run = 0;
        for (int d = 0; d <= MAXD; d++) {
            int c = bcnt[d];
            bbase[d] = run;
            int pad = (c + 3) & ~3;
            for (int i = c; i < pad; i++) order[run + i] = -1;
            run += pad;
        }
        for (int i = run; i < ORDER_SZ; i++) order[i] = -1;
    }
}

// ---- FUSED: scan level 3 (final off)  +  degree-bucket scatter (cnt-based) ----
__global__ void k_scan3_bucket(int* __restrict__ off, const int* __restrict__ bsum,
                               const int4* __restrict__ cnt4, const int* __restrict__ bbase,
                               int* __restrict__ bfill, int* __restrict__ order) {
    __shared__ int hist[16];
    __shared__ int base[16];
    int t = threadIdx.x;
    if (t < 16) hist[t] = 0;
    __syncthreads();
    int idx = blockIdx.x * 256 + t;
    if (idx == 0) off[NSEG] = Ne;
    if (idx < NSEG) off[idx] = off[idx] + bsum[blockIdx.x];
    int d = 0, rk = 0;
    bool valid = (idx < Nn);
    if (valid) {
        int4 c = cnt4[idx];
        d = min(c.x + c.y + c.z + c.w, MAXD);
        rk = atomicAdd(&hist[d], 1);
    }
    __syncthreads();
    if (t < 16) {
        int h = hist[t];
        base[t] = (h > 0) ? atomicAdd(&bfill[t], h) : 0;
    }
    __syncthreads();
    if (valid) order[bbase[d] + base[d] + rk] = idx | (d << 20);
}

// ---- scatter edges into segment-sorted order: NO atomics (rank precomputed) ----
__global__ void k_scatter(const int* __restrict__ eidx, const int* __restrict__ seg,
                          const int* __restrict__ rank, const int* __restrict__ off,
                          int* __restrict__ sorted_src) {
    int e = blockIdx.x * 256 + threadIdx.x;
    if (e >= Ne) return;
    int pos = off[seg[e]] + rank[e];
    sorted_src[pos] = eidx[e];
}

// classify edge ee via wave-uniform boundaries -> 4 uniform scalar scales
#define ACCS(v, ee)  {                                      \
    int rr = ((ee) >= e1) + ((ee) >= e2) + ((ee) >= e3);    \
    float s0 = (rr == 0) ? i0 : 0.f;                        \
    float s1 = (rr == 1) ? i1 : 0.f;                        \
    float s2 = (rr == 2) ? i2 : 0.f;                        \
    float s3 = (rr == 3) ? i3 : 0.f;                        \
    a0 = fmaf(s0, (v), a0);                                 \
    a1 = fmaf(s1, (v), a1);                                 \
    a2 = fmaf(s2, (v), a2);                                 \
    a3 = fmaf(s3, (v), a3); }

#define H16(ptr, s) __half2float((ptr)[(size_t)(s) * Hd + lane])

// ---- RGCN gather: 16-deep unrolled fp16 gather -> rel-major means aggR (fp32) ----
__global__ __launch_bounds__(256) void k_rgcn_gather(
        const __half* __restrict__ hin16, const int* __restrict__ off,
        const int* __restrict__ ssrc, float* __restrict__ aggR) {
    int tid = threadIdx.x;
    int wv = tid >> 6, lane = tid & 63;
    int wave = rfl(blockIdx.x * 4 + wv);
    int n0 = wave * 4;
    for (int i = 0; i < 4; i++) {
        int n = n0 + i;
        int nb = n * Rr;
        int e0 = rfl(off[nb]);
        int e1 = rfl(off[nb + 1]);
        int e2 = rfl(off[nb + 2]);
        int e3 = rfl(off[nb + 3]);
        int e4 = rfl(off[nb + 4]);
        float i0 = (e1 > e0) ? 1.f / (float)(e1 - e0) : 0.f;
        float i1 = (e2 > e1) ? 1.f / (float)(e2 - e1) : 0.f;
        float i2 = (e3 > e2) ? 1.f / (float)(e3 - e2) : 0.f;
        float i3 = (e4 > e3) ? 1.f / (float)(e4 - e3) : 0.f;
        float a0 = 0.f, a1 = 0.f, a2 = 0.f, a3 = 0.f;
        int e = e0;
        for (; e + 16 <= e4; e += 16) {             // 16 loads in flight
            const int4 sA = *(const int4*)(ssrc + e);
            const int4 sB = *(const int4*)(ssrc + e + 4);
            const int4 sC = *(const int4*)(ssrc + e + 8);
            const int4 sD = *(const int4*)(ssrc + e + 12);
            float v0 = H16(hin16, sA.x);
            float v1 = H16(hin16, sA.y);
            float v2 = H16(hin16, sA.z);
            float v3 = H16(hin16, sA.w);
            float v4 = H16(hin16, sB.x);
            float v5 = H16(hin16, sB.y);
            float v6 = H16(hin16, sB.z);
            float v7 = H16(hin16, sB.w);
            float v8 = H16(hin16, sC.x);
            float v9 = H16(hin16, sC.y);
            float vA = H16(hin16, sC.z);
            float vB = H16(hin16, sC.w);
            float vC = H16(hin16, sD.x);
            float vD = H16(hin16, sD.y);
            float vE = H16(hin16, sD.z);
            float vF = H16(hin16, sD.w);
            ACCS(v0, e + 0);  ACCS(v1, e + 1);  ACCS(v2, e + 2);  ACCS(v3, e + 3);
            ACCS(v4, e + 4);  ACCS(v5, e + 5);  ACCS(v6, e + 6);  ACCS(v7, e + 7);
            ACCS(v8, e + 8);  ACCS(v9, e + 9);  ACCS(vA, e + 10); ACCS(vB, e + 11);
            ACCS(vC, e + 12); ACCS(vD, e + 13); ACCS(vE, e + 14); ACCS(vF, e + 15);
        }
        for (; e + 4 <= e4; e += 4) {
            const int4 sA = *(const int4*)(ssrc + e);
            float v0 = H16(hin16, sA.x);
            float v1 = H16(hin16, sA.y);
            float v2 = H16(hin16, sA.z);
            float v3 = H16(hin16, sA.w);
            ACCS(v0, e + 0); ACCS(v1, e + 1); ACCS(v2, e + 2); ACCS(v3, e + 3);
        }
        for (; e < e4; e++) {
            int s = rfl(ssrc[e]);
            float v = H16(hin16, s);
            ACCS(v, e);
        }
        aggR[((size_t)0 * Nn + n) * Hd + lane] = a0;   // means (inv folded)
        aggR[((size_t)1 * Nn + n) * Hd + lane] = a1;
        aggR[((size_t)2 * Nn + n) * Hd + lane] = a2;
        aggR[((size_t)3 * Nn + n) * Hd + lane] = a3;
    }
}

// ---- RGCN transform as tiled GEMM: out = relu(b + [hin|mean0..3] @ [Wroot;W]) ----
// fp32 compute; epilogue also writes the fp16 shadow for the next gather.
__global__ __launch_bounds__(256) void k_rgcn_gemm(
        const float* __restrict__ hin, const float* __restrict__ aggR,
        const float* __restrict__ W, const float* __restrict__ Wroot,
        const float* __restrict__ bias, float* __restrict__ hout,
        __half* __restrict__ hout16) {
    __shared__ float As[64 * LDA];                  // 17 KB, padded rows
    __shared__ float Bs[64 * 64];                   // 16 KB
    int tid = threadIdx.x;
    int n0 = blockIdx.x * 64;
    int wv = tid >> 6, lane = tid & 63;
    int r = lane >> 4, c = lane & 15;
    int row_base = wv * 16 + 4 * r;                 // 4 consecutive A rows per lane
    float acc[4][4];
    #pragma unroll
    for (int i = 0; i < 4; i++)
        #pragma unroll
        for (int j = 0; j < 4; j++) acc[i][j] = 0.f;
    for (int p = 0; p < 5; p++) {
        const float* Bsrc = (p == 0) ? Wroot : (W + (size_t)(p - 1) * Hd * Hd);
        #pragma unroll
        for (int q = 0; q < 4; q++) {
            int idx = q * 256 + tid;                // 0..1023 float4 slots
            int arow = idx >> 4;
            int ac4 = idx & 15;
            int n = n0 + arow; if (n >= Nn) n = Nn - 1;
            const float* asrc = (p == 0) ? (hin + (size_t)n * Hd)
                                         : (aggR + ((size_t)(p - 1) * Nn + n) * Hd);
            *(float4*)&As[arow * LDA + ac4 * 4] = *(const float4*)(asrc + ac4 * 4);
            *(float4*)&Bs[idx * 4] = *(const float4*)(Bsrc + idx * 4);
        }
        __syncthreads();
        for (int k4 = 0; k4 < 64; k4 += 4) {
            float4 aa[4], bb[4];
            #pragma unroll
            for (int i = 0; i < 4; i++)
                aa[i] = *(float4*)&As[(row_base + i) * LDA + k4];
            #pragma unroll
            for (int kk = 0; kk < 4; kk++)
                bb[kk] = *(float4*)&Bs[(k4 + kk) * 64 + c * 4];
            #pragma unroll
            for (int i = 0; i < 4; i++) {
                acc[i][0] += aa[i].x * bb[0].x + aa[i].y * bb[1].x
                           + aa[i].z * bb[2].x + aa[i].w * bb[3].x;
                acc[i][1] += aa[i].x * bb[0].y + aa[i].y * bb[1].y
                           + aa[i].z * bb[2].y + aa[i].w * bb[3].y;
                acc[i][2] += aa[i].x * bb[0].z + aa[i].y * bb[1].z
                           + aa[i].z * bb[2].z + aa[i].w * bb[3].z;
                acc[i][3] += aa[i].x * bb[0].w + aa[i].y * bb[1].w
                           + aa[i].z * bb[2].w + aa[i].w * bb[3].w;
            }
        }
        __syncthreads();
    }
    float4 bj = *(const float4*)(bias + c * 4);
    #pragma unroll
    for (int i = 0; i < 4; i++) {
        int n = n0 + row_base + i;
        if (n < Nn) {
            float4 o;
            o.x = reluf(acc[i][0] + bj.x);
            o.y = reluf(acc[i][1] + bj.y);
            o.z = reluf(acc[i][2] + bj.z);
            o.w = reluf(acc[i][3] + bj.w);
            *(float4*)&hout[(size_t)n * Hd + c * 4] = o;
            __half2* d16 = (__half2*)&hout16[(size_t)n * Hd + c * 4];
            d16[0] = __floats2half2_rn(o.x, o.y);
            d16[1] = __floats2half2_rn(o.z, o.w);
        }
    }
}

// ---- FUSED MFConv layer: 16-deep fp16 gather + degree-bucketed transform ----
// (R10 shape: per-wave weight streams from hot L2, no barrier, 4-aligned buckets.)
__global__ __launch_bounds__(256) void k_mf_fused(
        const float* __restrict__ hin, const __half* __restrict__ hin16,
        const int* __restrict__ off, const int* __restrict__ ssrc,
        const int* __restrict__ order, const float* __restrict__ Wl,
        const float* __restrict__ bl, const float* __restrict__ Wr,
        float* __restrict__ hout, __half* __restrict__ hout16, int relu_out) {
    __shared__ float lds[4][4][Hd];                 // 4 KB: [wave][node][k]
    int tid = threadIdx.x;
    int wv = tid >> 6, lane = tid & 63;
    int slot0 = rfl(blockIdx.x * 16 + wv * 4);
    int ent[4];
    #pragma unroll
    for (int i = 0; i < 4; i++) ent[i] = rfl(order[slot0 + i]);
    int d = -1;
    #pragma unroll
    for (int i = 3; i >= 0; i--) if (ent[i] >= 0) d = ent[i] >> 20;
    if (d < 0) return;
    int n[4];
    #pragma unroll
    for (int i = 0; i < 4; i++) n[i] = (ent[i] >= 0) ? (ent[i] & 0xFFFFF) : 0;
    for (int i = 0; i < 4; i++) {
        int e0 = rfl(off[n[i] * Rr]);
        int e4 = rfl(off[n[i] * Rr + Rr]);
        float p0 = 0.f, p1 = 0.f, p2 = 0.f, p3 = 0.f;
        int e = e0;
        for (; e + 16 <= e4; e += 16) {
            const int4 sA = *(const int4*)(ssrc + e);
            const int4 sB = *(const int4*)(ssrc + e + 4);
            const int4 sC = *(const int4*)(ssrc + e + 8);
            const int4 sD = *(const int4*)(ssrc + e + 12);
            p0 += H16(hin16, sA.x) + H16(hin16, sA.y) + H16(hin16, sA.z) + H16(hin16, sA.w);
            p1 += H16(hin16, sB.x) + H16(hin16, sB.y) + H16(hin16, sB.z) + H16(hin16, sB.w);
            p2 += H16(hin16, sC.x) + H16(hin16, sC.y) + H16(hin16, sC.z) + H16(hin16, sC.w);
            p3 += H16(hin16, sD.x) + H16(hin16, sD.y) + H16(hin16, sD.z) + H16(hin16, sD.w);
        }
        for (; e + 4 <= e4; e += 4) {
            const int4 sA = *(const int4*)(ssrc + e);
            p0 += H16(hin16, sA.x) + H16(hin16, sA.y) + H16(hin16, sA.z) + H16(hin16, sA.w);
        }
        for (; e < e4; e++) {
            int s = rfl(ssrc[e]);
            p0 += H16(hin16, s);
        }
        lds[wv][i][lane] = (p0 + p1) + (p2 + p3);
    }
    const float* wl = Wl + (size_t)d * Hd * Hd;
    const float* wr = Wr + (size_t)d * Hd * Hd;
    float acc[4] = {0.f, 0.f, 0.f, 0.f};
    for (int kc = 0; kc < Hd; kc += 4) {
        float a0 = wl[(kc + 0) * Hd + lane];
        float a1 = wl[(kc + 1) * Hd + lane];
        float a2 = wl[(kc + 2) * Hd + lane];
        float a3 = wl[(kc + 3) * Hd + lane];
        float b0 = wr[(kc + 0) * Hd + lane];
        float b1 = wr[(kc + 1) * Hd + lane];
        float b2 = wr[(kc + 2) * Hd + lane];
        float b3 = wr[(kc + 3) * Hd + lane];
        #pragma unroll
        for (int i = 0; i < 4; i++) {
            const float4 av = *(const float4*)(&lds[wv][i][kc]);
            const float4 hv = *(const float4*)(hin + (size_t)n[i] * Hd + kc);
            acc[i] += av.x * a0 + av.y * a1 + av.z * a2 + av.w * a3
                    + hv.x * b0 + hv.y * b1 + hv.z * b2 + hv.w * b3;
        }
    }
    float bb = bl[d * Hd + lane];
    #pragma unroll
    for (int i = 0; i < 4; i++)
        if (ent[i] >= 0) {
            float v = acc[i] + bb;
            if (relu_out) {
                v = reluf(v);
                hout16[(size_t)n[i] * Hd + lane] = __float2half(v);  // next gather's shadow
            }
            hout[(size_t)n[i] * Hd + lane] = v;
        }
}

// ---- global add pool (batch_idx is sorted -> mostly single fused atomic) ----
__global__ void k_pool(const float* __restrict__ h, const int* __restrict__ batch,
                       float* __restrict__ g) {
    int wave = rfl((blockIdx.x * 256 + threadIdx.x) >> 6);
    int lane = threadIdx.x & 63;
    int n0 = wave * 4;
    if (n0 >= Nn) return;
    int b0 = batch[n0], b1 = batch[n0 + 1], b2 = batch[n0 + 2], b3 = batch[n0 + 3];
    float v0 = h[(size_t)n0 * Hd + lane];
    float v1 = h[(size_t)(n0 + 1) * Hd + lane];
    float v2 = h[(size_t)(n0 + 2) * Hd + lane];
    float v3 = h[(size_t)(n0 + 3) * Hd + lane];
    if (b0 == b1 && b0 == b2 && b0 == b3) {
        unsafeAtomicAdd(&g[(size_t)b0 * Hd + lane], v0 + v1 + v2 + v3);
    } else {
        unsafeAtomicAdd(&g[(size_t)b0 * Hd + lane], v0);
        unsafeAtomicAdd(&g[(size_t)b1 * Hd + lane], v1);
        unsafeAtomicAdd(&g[(size_t)b2 * Hd + lane], v2);
        unsafeAtomicAdd(&g[(size_t)b3 * Hd + lane], v3);
    }
}

// ---- head: relu(g@lin1+b1)@lin2+b2, one wave per graph ----
__global__ void k_head(const float* __restrict__ g, const float* __restrict__ w1,
                       const float* __restrict__ b1, const float* __restrict__ w2,
                       const float* __restrict__ b2, float* __restrict__ out) {
    __shared__ float t[4][Hd];
    int wv = threadIdx.x >> 6;
    int lane = threadIdx.x & 63;
    int gi = blockIdx.x * 4 + wv;
    float acc = b1[lane];
    for (int k = 0; k < Hd; k++) acc += g[(size_t)gi * Hd + k] * w1[k * Hd + lane];
    t[wv][lane] = reluf(acc);
    __syncthreads();
    if (lane < Od) {
        float o = b2[lane];
        for (int k = 0; k < Hd; k++) o += t[wv][k] * w2[k * Od + lane];
        out[(size_t)gi * Od + lane] = o;
    }
}

extern "C" void kernel_launch(void* const* d_in, const int* in_sizes, int n_in,
                              void* d_out, int out_size, void* d_ws, size_t ws_size,
                              hipStream_t stream) {
    const float* x      = (const float*)d_in[0];
    const float* ea     = (const float*)d_in[1];
    const int*   eidx   = (const int*)d_in[2];
    const int*   batch  = (const int*)d_in[3];
    const float* emb    = (const float*)d_in[4];
    const float* lin1_w = (const float*)d_in[5];
    const float* lin1_b = (const float*)d_in[6];
    const float* lin2_w = (const float*)d_in[7];
    const float* lin2_b = (const float*)d_in[8];
    const float* rgcn_w[2]    = {(const float*)d_in[9],  (const float*)d_in[15]};
    const float* rgcn_root[2] = {(const float*)d_in[10], (const float*)d_in[16]};
    const float* rgcn_b[2]    = {(const float*)d_in[11], (const float*)d_in[17]};
    const float* mf_wl[2]     = {(const float*)d_in[12], (const float*)d_in[18]};
    const float* mf_bl[2]     = {(const float*)d_in[13], (const float*)d_in[19]};
    const float* mf_wr[2]     = {(const float*)d_in[14], (const float*)d_in[20]};

    char* p = (char*)d_ws;
    float* h0    = (float*)p; p += sizeof(float) * (size_t)Nn * Hd;
    float* h1    = (float*)p; p += sizeof(float) * (size_t)Nn * Hd;
    __half* h16a = (__half*)p; p += sizeof(__half) * (size_t)Nn * Hd;
    __half* h16b = (__half*)p; p += sizeof(__half) * (size_t)Nn * Hd;
    float* aggR  = (float*)p; p += sizeof(float) * (size_t)Rr * Nn * Hd;
    float* gbuf  = (float*)p; p += sizeof(float) * (size_t)Ng * Hd;
    int* seg     = (int*)p;   p += sizeof(int) * (size_t)Ne;
    int* rank    = (int*)p;   p += sizeof(int) * (size_t)Ne;
    int* ssrc    = (int*)p;   p += sizeof(int) * (size_t)Ne;
    int* cnt     = (int*)p;   p += sizeof(int) * (size_t)NSEG;  // contiguous with bcnt/bfill
    int* bcnt    = (int*)p;   p += sizeof(int) * 16;
    int* bfill   = (int*)p;   p += sizeof(int) * 16;
    int* off     = (int*)p;   p += sizeof(int) * (size_t)(NSEG + 1);
    int* bsum    = (int*)p;   p += sizeof(int) * 1024;
    int* bbase   = (int*)p;   p += sizeof(int) * 16;
    int* order   = (int*)p;   p += sizeof(int) * (size_t)ORDER_SZ;

    hipMemsetAsync(cnt, 0, sizeof(int) * ((size_t)NSEG + 32), stream);
    hipMemsetAsync(gbuf, 0, sizeof(float) * (size_t)Ng * Hd, stream);

    k_rel_emb<<<NB_RELSEG + NB_EMBED, 256, 0, stream>>>((const float4*)ea, eidx, seg, rank,
                                                        cnt, x, emb, h0, h16a);
    k_scan1<<<SCAN_BLK, 256, 0, stream>>>(cnt, off, bsum, bcnt);
    k_scan2<<<1, 1024, 0, stream>>>(bsum, bcnt, bbase, order);
    k_scan3_bucket<<<SCAN_BLK, 256, 0, stream>>>(off, bsum, (const int4*)cnt, bbase,
                                                 bfill, order);
    k_scatter<<<Ne / 256, 256, 0, stream>>>(eidx, seg, rank, off, ssrc);

    float* hin = h0;   __half* hin16 = h16a;
    float* hout = h1;  __half* hout16 = h16b;
    for (int b = 0; b < 2; b++) {
        k_rgcn_gather<<<NB_RG, 256, 0, stream>>>(hin16, off, ssrc, aggR);
        k_rgcn_gemm<<<NB_GEMM, 256, 0, stream>>>(hin, aggR, rgcn_w[b], rgcn_root[b],
                                                 rgcn_b[b], hout, hout16);
        k_mf_fused<<<NB_MF, 256, 0, stream>>>(hout, hout16, off, ssrc, order, mf_wl[b],
                                              mf_bl[b], mf_wr[b], hin, hin16,
                                              b == 0 ? 1 : 0);
        // block output is back in hin (fp32) + hin16 (shadow, b=0 only; b=1 feeds pool)
    }
    k_pool<<<Nn / 16, 256, 0, stream>>>(hin, batch, gbuf);
    k_head<<<Ng / 4, 256, 0, stream>>>(gbuf, lin1_w, lin1_b, lin2_w, lin2_b, (float*)d_out);
}